// Round 8
// baseline (801.208 us; speedup 1.0000x reference)
//
#include <hip/hip_runtime.h>

#define NN 50000
#define NE 1600000
#define FILL_B 1563   // ceil((NE/4)/256)
#define EMB_B  782    // ceil((NN*4)/256)
#define HIST_STRIDE 100096 // 391 blocks * 256 threads
constexpr float LN_EPS = 1e-5f;

typedef _Float16 half8 __attribute__((ext_vector_type(8)));

__device__ __forceinline__ float gelu_f(float x){
  float ax = fabsf(x) * 0.70710678118654752440f;
  float t  = __builtin_amdgcn_rcpf(fmaf(0.3275911f, ax, 1.0f));
  float e  = __expf(-ax*ax);
  float p  = t*fmaf(t, fmaf(t, fmaf(t, fmaf(t, 1.061405429f, -1.453152027f),
                                    1.421413741f), -0.284496736f), 0.254829592f);
  float er = fmaf(-p, e, 1.0f);
  return 0.5f * x * (1.0f + copysignf(er, x));
}

__device__ __forceinline__ void ld8(const float* __restrict__ p, float* r){
  float4 a=((const float4*)p)[0], b=((const float4*)p)[1];
  r[0]=a.x;r[1]=a.y;r[2]=a.z;r[3]=a.w;r[4]=b.x;r[5]=b.y;r[6]=b.z;r[7]=b.w;
}
__device__ __forceinline__ void ld16(const float* __restrict__ p, float* r){ ld8(p,r); ld8(p+8,r+8); }
__device__ __forceinline__ void st8(float* __restrict__ p, const float* r){
  float4 a,b; a.x=r[0];a.y=r[1];a.z=r[2];a.w=r[3]; b.x=r[4];b.y=r[5];b.z=r[6];b.w=r[7];
  ((float4*)p)[0]=a; ((float4*)p)[1]=b;
}

// ---------------- hist: 4 int4 chunks/thread, 16 atomics in flight ----------------
__global__ __launch_bounds__(256) void hist_kernel(const int* __restrict__ ei,
    int* __restrict__ cnt, int* __restrict__ rank){
  int t = blockIdx.x*256 + threadIdx.x;   // 0..HIST_STRIDE-1
  int i0 = t, i1 = t + HIST_STRIDE, i2 = t + 2*HIST_STRIDE, i3 = t + 3*HIST_STRIDE;
  bool v0 = i0 < NE/4, v1 = i1 < NE/4, v2 = i2 < NE/4, v3 = i3 < NE/4;
  int4 d0 = v0 ? ((const int4*)(ei + NE))[i0] : make_int4(0,0,0,0);
  int4 d1 = v1 ? ((const int4*)(ei + NE))[i1] : make_int4(0,0,0,0);
  int4 d2 = v2 ? ((const int4*)(ei + NE))[i2] : make_int4(0,0,0,0);
  int4 d3 = v3 ? ((const int4*)(ei + NE))[i3] : make_int4(0,0,0,0);
  int4 r0, r1, r2, r3;
  if(v0){ r0.x = atomicAdd(&cnt[d0.x],1); r0.y = atomicAdd(&cnt[d0.y],1);
          r0.z = atomicAdd(&cnt[d0.z],1); r0.w = atomicAdd(&cnt[d0.w],1); }
  if(v1){ r1.x = atomicAdd(&cnt[d1.x],1); r1.y = atomicAdd(&cnt[d1.y],1);
          r1.z = atomicAdd(&cnt[d1.z],1); r1.w = atomicAdd(&cnt[d1.w],1); }
  if(v2){ r2.x = atomicAdd(&cnt[d2.x],1); r2.y = atomicAdd(&cnt[d2.y],1);
          r2.z = atomicAdd(&cnt[d2.z],1); r2.w = atomicAdd(&cnt[d2.w],1); }
  if(v3){ r3.x = atomicAdd(&cnt[d3.x],1); r3.y = atomicAdd(&cnt[d3.y],1);
          r3.z = atomicAdd(&cnt[d3.z],1); r3.w = atomicAdd(&cnt[d3.w],1); }
  if(v0) ((int4*)rank)[i0] = r0;
  if(v1) ((int4*)rank)[i1] = r1;
  if(v2) ((int4*)rank)[i2] = r2;
  if(v3) ((int4*)rank)[i3] = r3;
}

#define CHUNK 52
__global__ __launch_bounds__(1024) void scan_kernel(const int* __restrict__ deg, int* __restrict__ row_ptr){
  __shared__ int sums[1024];
  int t = threadIdx.x;
  int base = t*CHUNK;
  int4 v[13];
  int ssum = 0;
  #pragma unroll
  for(int i=0;i<13;i++){
    int idx = base + 4*i;
    if(idx + 3 < NN){
      v[i] = ((const int4*)deg)[(base>>2)+i];
    } else {
      v[i].x = (idx+0<NN)?deg[idx+0]:0; v[i].y = (idx+1<NN)?deg[idx+1]:0;
      v[i].z = (idx+2<NN)?deg[idx+2]:0; v[i].w = (idx+3<NN)?deg[idx+3]:0;
    }
    ssum += v[i].x + v[i].y + v[i].z + v[i].w;
  }
  sums[t]=ssum;
  __syncthreads();
  for(int off=1; off<1024; off<<=1){
    int vv = (t>=off) ? sums[t-off] : 0;
    __syncthreads();
    sums[t] += vv;
    __syncthreads();
  }
  int run = (t>0) ? sums[t-1] : 0;
  #pragma unroll
  for(int i=0;i<13;i++){
    int idx = base + 4*i;
    int4 o;
    o.x = run; run += v[i].x;
    o.y = run; run += v[i].y;
    o.z = run; run += v[i].z;
    o.w = run; run += v[i].w;
    if(idx + 3 < NN){
      ((int4*)row_ptr)[(base>>2)+i] = o;
    } else {
      if(idx+0<NN) row_ptr[idx+0]=o.x;
      if(idx+1<NN) row_ptr[idx+1]=o.y;
      if(idx+2<NN) row_ptr[idx+2]=o.z;
      if(idx+3<NN) row_ptr[idx+3]=o.w;
    }
  }
  if(t==1023) row_ptr[NN] = sums[1023];
}

__global__ __launch_bounds__(256) void fill_kernel(const int* __restrict__ ei,
    const int* __restrict__ row_ptr, const int* __restrict__ rank, int* __restrict__ csr_src){
  int t = blockIdx.x*256 + threadIdx.x;
  if(t < NE/4){
    int4 d  = ((const int4*)(ei + NE))[t];
    int4 sv = ((const int4*)ei)[t];
    int4 rk = ((const int4*)rank)[t];
    csr_src[row_ptr[d.x] + rk.x] = sv.x;
    csr_src[row_ptr[d.y] + rk.y] = sv.y;
    csr_src[row_ptr[d.z] + rk.z] = sv.z;
    csr_src[row_ptr[d.w] + rk.w] = sv.w;
  }
}

// ---------------- embed MLP + layer-0 PQR, 4 lanes/node ----------------
__global__ __launch_bounds__(256) void embed_pqr_kernel(
    const float* __restrict__ x,
    const float* __restrict__ W1, const float* __restrict__ b1,
    const float* __restrict__ g1, const float* __restrict__ bb1,
    const float* __restrict__ W2, const float* __restrict__ b2,
    const float* __restrict__ g2, const float* __restrict__ bb2,
    const float* __restrict__ Wm, const float* __restrict__ bm,
    const float* __restrict__ Wu, const float* __restrict__ bu,
    const float* __restrict__ fb1, const float* __restrict__ fbng, const float* __restrict__ fbnb,
    float* __restrict__ h, float* __restrict__ pre,
    float* __restrict__ P, _Float16* __restrict__ Qh, float* __restrict__ R,
    float* __restrict__ cvec)
{
  int t = blockIdx.x*256 + threadIdx.x;
  const float rs = rsqrtf(1.0f + LN_EPS);
  if(t < 64) cvec[t] = fmaf(fb1[t], fbng[t]*rs, fbnb[t]);
  int n = t >> 2, q = t & 3;
  if(n >= NN) return;
  int base = threadIdx.x & 60;
  float4 xq = ((const float4*)x)[n*4 + q];
  float xv[16];
  #pragma unroll
  for(int m=0;m<4;m++){
    xv[4*m+0]=__shfl(xq.x, base|m);
    xv[4*m+1]=__shfl(xq.y, base|m);
    xv[4*m+2]=__shfl(xq.z, base|m);
    xv[4*m+3]=__shfl(xq.w, base|m);
  }
  float a1q[16]; ld16(b1 + q*16, a1q);
  #pragma unroll
  for(int k=0;k<16;k++){
    float w[16]; ld16(W1 + k*64 + q*16, w);
    float xk = xv[k];
    #pragma unroll
    for(int j=0;j<16;j++) a1q[j] += xk * w[j];
  }
  { float g[16], b[16]; ld16(g1+q*16,g); ld16(bb1+q*16,b);
    #pragma unroll
    for(int j=0;j<16;j++) a1q[j] = gelu_f(a1q[j]*(g[j]*rs) + b[j]); }
  float hq[8]; ld8(b2 + q*8, hq);
  #pragma unroll
  for(int m=0;m<4;m++){
    #pragma unroll
    for(int kk=0;kk<16;kk++){
      float a = __shfl(a1q[kk], base|m);
      float w[8]; ld8(W2 + (m*16+kk)*32 + q*8, w);
      #pragma unroll
      for(int j=0;j<8;j++) hq[j] += a * w[j];
    }
  }
  { float g[8], b[8]; ld8(g2+q*8,g); ld8(bb2+q*8,b);
    #pragma unroll
    for(int j=0;j<8;j++) hq[j] = gelu_f(hq[j]*(g[j]*rs) + b[j]); }
  st8(h   + (size_t)n*32 + q*8, hq);
  st8(pre + (size_t)n*32 + q*8, hq);
  float apv[8], aqv[8], arv[8];
  ld8(bm+q*8, apv); ld8(bu+q*8, arv);
  #pragma unroll
  for(int j=0;j<8;j++) aqv[j]=0.f;
  #pragma unroll
  for(int m=0;m<4;m++){
    #pragma unroll
    for(int kk=0;kk<8;kk++){
      float hk = __shfl(hq[kk], base|m);
      int k = m*8+kk;
      float wm[8],wq[8],wu[8];
      ld8(Wm + k*32      + q*8, wm);
      ld8(Wm + (32+k)*32 + q*8, wq);
      ld8(Wu + k*32      + q*8, wu);
      #pragma unroll
      for(int j=0;j<8;j++){ apv[j]+=hk*wm[j]; aqv[j]+=hk*wq[j]; arv[j]+=hk*wu[j]; }
    }
  }
  st8(P + (size_t)n*32 + q*8, apv);
  st8(R + (size_t)n*32 + q*8, arv);
  half8 qo;
  #pragma unroll
  for(int k=0;k<8;k++) qo[k] = (_Float16)aqv[k];
  *(half8*)(Qh + (size_t)n*32 + q*8) = qo;
}

// ======== msg gather phase (shared): produces agg8 in every lane ========
__device__ __forceinline__ void msg_gather(
    const float* __restrict__ P, const _Float16* __restrict__ Qin,
    const int* __restrict__ row_ptr, const int* __restrict__ csr_src,
    const float* __restrict__ mg, const float* __restrict__ mb,
    int n, int slot, int q, float* agg8)
{
  float mgq[8], mbq[8], p8[8];
  ld8(mg + q*8, mgq); ld8(mb + q*8, mbq);
  ld8(P + (size_t)n*32 + q*8, p8);
  #pragma unroll
  for(int k=0;k<8;k++) agg8[k]=0.f;
  int e0 = row_ptr[n], e1 = row_ptr[n+1];
  int e = e0 + slot;
  int src = (e < e1) ? csr_src[e] : 0;
  half8 qv = *(const half8*)(Qin + (size_t)src*32 + q*8);
  while(e < e1){
    int e2 = e + 4;
    int src2 = (e2 < e1) ? csr_src[e2] : 0;
    half8 qv2 = *(const half8*)(Qin + (size_t)src2*32 + q*8);
    float v[8];
    #pragma unroll
    for(int k=0;k<8;k++) v[k] = p8[k] + (float)qv[k];
    float ps = ((v[0]+v[1])+(v[2]+v[3])) + ((v[4]+v[5])+(v[6]+v[7]));
    ps += __shfl_xor(ps,1); ps += __shfl_xor(ps,2);
    float mean = ps * 0.03125f;
    float vs = 0.f;
    #pragma unroll
    for(int k=0;k<8;k++){ float dd = v[k]-mean; vs += dd*dd; v[k]=dd; }
    vs += __shfl_xor(vs,1); vs += __shfl_xor(vs,2);
    float rstd = rsqrtf(vs*0.03125f + LN_EPS);
    #pragma unroll
    for(int k=0;k<8;k++) agg8[k] += gelu_f(v[k]*rstd*mgq[k] + mbq[k]);
    qv = qv2; e = e2;
  }
  #pragma unroll
  for(int k=0;k<8;k++) agg8[k] += __shfl_xor(agg8[k], 4);
  #pragma unroll
  for(int k=0;k<8;k++) agg8[k] += __shfl_xor(agg8[k], 8);
}

// ======== shared update tail: returns new hq (residual applied) ========
__device__ __forceinline__ void upd_tail(
    const float* __restrict__ R, float* __restrict__ h,
    const float* __restrict__ Ub, const float* __restrict__ ug, const float* __restrict__ ub,
    int n, int slot, int q, int b4, const float* agg8, float* hq)
{
  float uq[8]; ld8(R + (size_t)n*32 + q*8, uq);
  #pragma unroll
  for(int m=0;m<4;m++){
    #pragma unroll
    for(int kk=0;kk<8;kk++){
      float a = __shfl(agg8[kk], b4|m);
      float w[8]; ld8(Ub + (m*8+kk)*32 + q*8, w);
      #pragma unroll
      for(int j=0;j<8;j++) uq[j] += a * w[j];
    }
  }
  float sm = ((uq[0]+uq[1])+(uq[2]+uq[3])) + ((uq[4]+uq[5])+(uq[6]+uq[7]));
  sm += __shfl_xor(sm,1); sm += __shfl_xor(sm,2);
  float mean = sm * 0.03125f;
  float vs = 0.f;
  #pragma unroll
  for(int j=0;j<8;j++){ float d = uq[j]-mean; vs += d*d; uq[j]=d; }
  vs += __shfl_xor(vs,1); vs += __shfl_xor(vs,2);
  float rstd = rsqrtf(vs*0.03125f + LN_EPS);
  float ugq[8], ubq[8];
  ld8(ug+q*8, ugq); ld8(ub+q*8, ubq);
  ld8(h + (size_t)n*32 + q*8, hq);
  #pragma unroll
  for(int j=0;j<8;j++) hq[j] += gelu_f(uq[j]*rstd*ugq[j] + ubq[j]);
  if(slot==0) st8(h + (size_t)n*32 + q*8, hq);
}

// -------- msg + update + next-layer PQR (layers 0,1) --------
__global__ __launch_bounds__(256) void msg_upd_kernel(
    float* __restrict__ P, const _Float16* __restrict__ Qin,
    float* __restrict__ R, float* __restrict__ h,
    const int* __restrict__ row_ptr, const int* __restrict__ csr_src,
    const float* __restrict__ mg, const float* __restrict__ mb,
    const float* __restrict__ Ub,
    const float* __restrict__ ug, const float* __restrict__ ub,
    const float* __restrict__ Wm2, const float* __restrict__ bm2,
    const float* __restrict__ Wu2, const float* __restrict__ bu2,
    _Float16* __restrict__ Qout)
{
  int tid = blockIdx.x*256 + threadIdx.x;   // grid = NN*16 exactly
  int n = tid >> 4, s = tid & 15;
  int slot = s >> 2, q = s & 3;
  int b4 = (threadIdx.x & 63) & 60;
  float agg8[8];
  msg_gather(P, Qin, row_ptr, csr_src, mg, mb, n, slot, q, agg8);
  float hq[8];
  upd_tail(R, h, Ub, ug, ub, n, slot, q, b4, agg8, hq);
  // next-layer PQR from new h
  float apv[8], aqv[8], arv[8];
  ld8(bm2+q*8, apv); ld8(bu2+q*8, arv);
  #pragma unroll
  for(int j=0;j<8;j++) aqv[j]=0.f;
  #pragma unroll
  for(int m=0;m<4;m++){
    #pragma unroll
    for(int kk=0;kk<8;kk++){
      float hk = __shfl(hq[kk], b4|m);
      int k = m*8+kk;
      float wm[8],wq[8],wu[8];
      ld8(Wm2 + k*32      + q*8, wm);
      ld8(Wm2 + (32+k)*32 + q*8, wq);
      ld8(Wu2 + k*32      + q*8, wu);
      #pragma unroll
      for(int j=0;j<8;j++){ apv[j]+=hk*wm[j]; aqv[j]+=hk*wq[j]; arv[j]+=hk*wu[j]; }
    }
  }
  if(slot==0){
    st8(P + (size_t)n*32 + q*8, apv);
    st8(R + (size_t)n*32 + q*8, arv);
    half8 qo;
    #pragma unroll
    for(int k=0;k<8;k++) qo[k] = (_Float16)aqv[k];
    *(half8*)(Qout + (size_t)n*32 + q*8) = qo;
  }
}

// -------- msg + update + final node matmul (layer 2) --------
__global__ __launch_bounds__(256) void msg_fin_kernel(
    float* __restrict__ P, const _Float16* __restrict__ Qin,
    float* __restrict__ R, float* __restrict__ h,
    const int* __restrict__ row_ptr, const int* __restrict__ csr_src,
    const float* __restrict__ mg, const float* __restrict__ mb,
    const float* __restrict__ Ub,
    const float* __restrict__ ug, const float* __restrict__ ub,
    const float* __restrict__ pre,
    const float* __restrict__ fW1, const float* __restrict__ fbng,
    _Float16* __restrict__ y1, _Float16* __restrict__ y2)
{
  int tid = blockIdx.x*256 + threadIdx.x;
  int n = tid >> 4, s = tid & 15;
  int slot = s >> 2, q = s & 3;
  int b4 = (threadIdx.x & 63) & 60;
  const float rs = rsqrtf(1.0f + LN_EPS);
  float agg8[8];
  msg_gather(P, Qin, row_ptr, csr_src, mg, mb, n, slot, q, agg8);
  float hq[8];
  upd_tail(R, h, Ub, ug, ub, n, slot, q, b4, agg8, hq);
  float pq[8]; ld8(pre + (size_t)n*32 + q*8, pq);
  #pragma unroll
  for(int j=0;j<8;j++) hq[j] += pq[j];
  float acc[16];
  #pragma unroll
  for(int j=0;j<16;j++) acc[j]=0.f;
  #pragma unroll
  for(int m=0;m<4;m++){
    #pragma unroll
    for(int kk=0;kk<8;kk++){
      float hk = __shfl(hq[kk], b4|m);
      float w[16]; ld16(fW1 + (m*8+kk)*64 + q*16, w);
      #pragma unroll
      for(int j=0;j<16;j++) acc[j] += hk * w[j];
    }
  }
  if(slot==0){
    float fg[16]; ld16(fbng + q*16, fg);
    half8 o0, o1;
    #pragma unroll
    for(int k=0;k<8;k++){
      o0[k] = (_Float16)(acc[k]   * (fg[k]*rs));
      o1[k] = (_Float16)(acc[8+k] * (fg[8+k]*rs));
    }
    _Float16* dst = (q<2) ? (y1 + (size_t)n*32 + q*16) : (y2 + (size_t)n*32 + (q-2)*16);
    ((half8*)dst)[0] = o0; ((half8*)dst)[1] = o1;
  }
}

// ---------------- final per-edge: 4 lanes per edge, feature-split passes ----------------
__global__ __launch_bounds__(256) void finalA_kernel(
    const _Float16* __restrict__ y, const int* __restrict__ ei,
    const float* __restrict__ cvec, const float* __restrict__ W2,
    const float* __restrict__ b2, float* __restrict__ out)
{
  int t = blockIdx.x*256 + threadIdx.x;   // grid = NE*4 exactly
  int e = t >> 2, q = t & 3;
  int s = __builtin_nontemporal_load(ei + e);
  int d = __builtin_nontemporal_load(ei + NE + e);
  half8 a8 = *(const half8*)(y + (size_t)d*32 + q*8);
  half8 c8 = *(const half8*)(y + (size_t)s*32 + q*8);
  float cq[8]; ld8(cvec + q*8, cq);
  float w[24]; ld8(W2+q*24, w); ld8(W2+q*24+8, w+8); ld8(W2+q*24+16, w+16);
  float o0=0.f,o1=0.f,o2=0.f;
  #pragma unroll
  for(int k=0;k<8;k++){
    float tt = gelu_f(((float)a8[k]-(float)c8[k]) + cq[k]);
    o0 += tt*w[3*k]; o1 += tt*w[3*k+1]; o2 += tt*w[3*k+2];
  }
  o0 += __shfl_xor(o0,1); o0 += __shfl_xor(o0,2);
  o1 += __shfl_xor(o1,1); o1 += __shfl_xor(o1,2);
  o2 += __shfl_xor(o2,1); o2 += __shfl_xor(o2,2);
  float ov = (q==0) ? o0 + b2[0] : (q==1) ? o1 + b2[1] : o2 + b2[2];
  if(q < 3) __builtin_nontemporal_store(ov, out + (size_t)e*3 + q);
}

__global__ __launch_bounds__(256) void finalB_kernel(
    const _Float16* __restrict__ y, const int* __restrict__ ei,
    const float* __restrict__ cvec, const float* __restrict__ W2,
    float* __restrict__ out)
{
  int t = blockIdx.x*256 + threadIdx.x;
  int e = t >> 2, q = t & 3;
  float prev = 0.f;
  if(q < 3) prev = __builtin_nontemporal_load(out + (size_t)e*3 + q);
  int s = __builtin_nontemporal_load(ei + e);
  int d = __builtin_nontemporal_load(ei + NE + e);
  half8 a8 = *(const half8*)(y + (size_t)d*32 + q*8);
  half8 c8 = *(const half8*)(y + (size_t)s*32 + q*8);
  float cq[8]; ld8(cvec + q*8, cq);
  float w[24]; ld8(W2+q*24, w); ld8(W2+q*24+8, w+8); ld8(W2+q*24+16, w+16);
  float o0=0.f,o1=0.f,o2=0.f;
  #pragma unroll
  for(int k=0;k<8;k++){
    float tt = gelu_f(((float)a8[k]-(float)c8[k]) + cq[k]);
    o0 += tt*w[3*k]; o1 += tt*w[3*k+1]; o2 += tt*w[3*k+2];
  }
  o0 += __shfl_xor(o0,1); o0 += __shfl_xor(o0,2);
  o1 += __shfl_xor(o1,1); o1 += __shfl_xor(o1,2);
  o2 += __shfl_xor(o2,1); o2 += __shfl_xor(o2,2);
  float ov = prev + ((q==0) ? o0 : (q==1) ? o1 : o2);
  if(q < 3) __builtin_nontemporal_store(ov, out + (size_t)e*3 + q);
}

extern "C" void kernel_launch(void* const* d_in, const int* in_sizes, int n_in,
                              void* d_out, int out_size, void* d_ws, size_t ws_size,
                              hipStream_t stream)
{
  (void)in_sizes; (void)n_in; (void)out_size; (void)ws_size;
  const float* x     = (const float*)d_in[0];
  const int*   ei    = (const int*)d_in[1];
  const float* eW1   = (const float*)d_in[2];
  const float* eb1   = (const float*)d_in[3];
  const float* ebn1g = (const float*)d_in[4];
  const float* ebn1b = (const float*)d_in[5];
  const float* eW2   = (const float*)d_in[6];
  const float* eb2   = (const float*)d_in[7];
  const float* ebn2g = (const float*)d_in[8];
  const float* ebn2b = (const float*)d_in[9];
  const float* msgW  = (const float*)d_in[10];
  const float* msgb  = (const float*)d_in[11];
  const float* msglng= (const float*)d_in[12];
  const float* msglnb= (const float*)d_in[13];
  const float* updW  = (const float*)d_in[14];
  const float* updb  = (const float*)d_in[15];
  const float* updlng= (const float*)d_in[16];
  const float* updlnb= (const float*)d_in[17];
  const float* fW1   = (const float*)d_in[18];
  const float* fb1   = (const float*)d_in[19];
  const float* fbng  = (const float*)d_in[20];
  const float* fbnb  = (const float*)d_in[21];
  const float* fW2   = (const float*)d_in[22];
  const float* fb2   = (const float*)d_in[23];
  float* out = (float*)d_out;

  // layout (floats): h, pre, P, R (NN*32 each), QA, QB, y2 (NN*16 each), cvec, ints
  float* f   = (float*)d_ws;
  float* h   = f;                         // rank aliases h (ints) — fill before embed
  float* pre = f + 1*(size_t)NN*32;
  float* P   = f + 2*(size_t)NN*32;
  float* R   = f + 3*(size_t)NN*32;
  float* QAf = f + 4*(size_t)NN*32;
  float* QBf = QAf + (size_t)NN*16;
  float* y2f = QBf + (size_t)NN*16;
  _Float16* QA = (_Float16*)QAf;
  _Float16* QB = (_Float16*)QBf;
  _Float16* y1 = (_Float16*)QBf;          // y1 aliases QB (dead at msg2)
  _Float16* y2 = (_Float16*)y2f;
  float* cvec  = y2f + (size_t)NN*16;     // 64 floats
  int* ip      = (int*)(cvec + 64);
  int* cnt     = ip;                      // NN
  int* row_ptr = ip + NN;                 // NN+4
  int* csr     = ip + 2*NN + 4;           // NE
  int* rank    = (int*)h;                 // NE ints (h written later by embed)

  hipMemsetAsync(cnt, 0, NN*sizeof(int), stream);
  hist_kernel<<<391, 256, 0, stream>>>(ei, cnt, rank);
  scan_kernel<<<1, 1024, 0, stream>>>(cnt, row_ptr);
  fill_kernel<<<FILL_B, 256, 0, stream>>>(ei, row_ptr, rank, csr);

  embed_pqr_kernel<<<EMB_B, 256, 0, stream>>>(x, eW1, eb1, ebn1g, ebn1b,
      eW2, eb2, ebn2g, ebn2b,
      msgW, msgb, updW, updb,
      fb1, fbng, fbnb,
      h, pre, P, QA, R, cvec);

  // layer 0: Qin=QA, Qout=QB
  msg_upd_kernel<<<(NN*16)/256, 256, 0, stream>>>(P, QA, R, h, row_ptr, csr,
      msglng + 0*32, msglnb + 0*32,
      updW + 0*2048 + 1024, updlng + 0*32, updlnb + 0*32,
      msgW + 1*2048, msgb + 1*32, updW + 1*2048, updb + 1*32, QB);
  // layer 1: Qin=QB, Qout=QA
  msg_upd_kernel<<<(NN*16)/256, 256, 0, stream>>>(P, QB, R, h, row_ptr, csr,
      msglng + 1*32, msglnb + 1*32,
      updW + 1*2048 + 1024, updlng + 1*32, updlnb + 1*32,
      msgW + 2*2048, msgb + 2*32, updW + 2*2048, updb + 2*32, QA);
  // layer 2: Qin=QA, writes y1 (aliases QB), y2
  msg_fin_kernel<<<(NN*16)/256, 256, 0, stream>>>(P, QA, R, h, row_ptr, csr,
      msglng + 2*32, msglnb + 2*32,
      updW + 2*2048 + 1024, updlng + 2*32, updlnb + 2*32,
      pre, fW1, fbng, y1, y2);

  finalA_kernel<<<(NE*4)/256, 256, 0, stream>>>(y1, ei, cvec,      fW2,      fb2, out);
  finalB_kernel<<<(NE*4)/256, 256, 0, stream>>>(y2, ei, cvec + 32, fW2 + 96, out);
}

// Round 9
// 523.646 us; speedup vs baseline: 1.5301x; 1.5301x over previous
//
#include <hip/hip_runtime.h>

#define NN 50000
#define NE 1600000
#define FILL_B 1563   // ceil((NE/4)/256)
#define EMB_B  782    // ceil((NN*4)/256)
#define HIST_STRIDE 100096 // 391 blocks * 256 threads
constexpr float LN_EPS = 1e-5f;

typedef _Float16 half8 __attribute__((ext_vector_type(8)));

__device__ __forceinline__ float gelu_f(float x){
  float ax = fabsf(x) * 0.70710678118654752440f;
  float t  = __builtin_amdgcn_rcpf(fmaf(0.3275911f, ax, 1.0f));
  float e  = __expf(-ax*ax);
  float p  = t*fmaf(t, fmaf(t, fmaf(t, fmaf(t, 1.061405429f, -1.453152027f),
                                    1.421413741f), -0.284496736f), 0.254829592f);
  float er = fmaf(-p, e, 1.0f);
  return 0.5f * x * (1.0f + copysignf(er, x));
}

__device__ __forceinline__ void ld8(const float* __restrict__ p, float* r){
  float4 a=((const float4*)p)[0], b=((const float4*)p)[1];
  r[0]=a.x;r[1]=a.y;r[2]=a.z;r[3]=a.w;r[4]=b.x;r[5]=b.y;r[6]=b.z;r[7]=b.w;
}
__device__ __forceinline__ void ld16(const float* __restrict__ p, float* r){ ld8(p,r); ld8(p+8,r+8); }
__device__ __forceinline__ void st8(float* __restrict__ p, const float* r){
  float4 a,b; a.x=r[0];a.y=r[1];a.z=r[2];a.w=r[3]; b.x=r[4];b.y=r[5];b.z=r[6];b.w=r[7];
  ((float4*)p)[0]=a; ((float4*)p)[1]=b;
}

// ---------------- hist: 4 int4 chunks/thread, 16 atomics in flight, 8 VGPR ----------------
__global__ __launch_bounds__(256) void hist_kernel(const int* __restrict__ ei,
    int* __restrict__ cnt, int* __restrict__ rank){
  int t = blockIdx.x*256 + threadIdx.x;
  int i0 = t, i1 = t + HIST_STRIDE, i2 = t + 2*HIST_STRIDE, i3 = t + 3*HIST_STRIDE;
  bool v0 = i0 < NE/4, v1 = i1 < NE/4, v2 = i2 < NE/4, v3 = i3 < NE/4;
  int4 d0 = v0 ? ((const int4*)(ei + NE))[i0] : make_int4(0,0,0,0);
  int4 d1 = v1 ? ((const int4*)(ei + NE))[i1] : make_int4(0,0,0,0);
  int4 d2 = v2 ? ((const int4*)(ei + NE))[i2] : make_int4(0,0,0,0);
  int4 d3 = v3 ? ((const int4*)(ei + NE))[i3] : make_int4(0,0,0,0);
  int4 r0, r1, r2, r3;
  if(v0){ r0.x = atomicAdd(&cnt[d0.x],1); r0.y = atomicAdd(&cnt[d0.y],1);
          r0.z = atomicAdd(&cnt[d0.z],1); r0.w = atomicAdd(&cnt[d0.w],1); }
  if(v1){ r1.x = atomicAdd(&cnt[d1.x],1); r1.y = atomicAdd(&cnt[d1.y],1);
          r1.z = atomicAdd(&cnt[d1.z],1); r1.w = atomicAdd(&cnt[d1.w],1); }
  if(v2){ r2.x = atomicAdd(&cnt[d2.x],1); r2.y = atomicAdd(&cnt[d2.y],1);
          r2.z = atomicAdd(&cnt[d2.z],1); r2.w = atomicAdd(&cnt[d2.w],1); }
  if(v3){ r3.x = atomicAdd(&cnt[d3.x],1); r3.y = atomicAdd(&cnt[d3.y],1);
          r3.z = atomicAdd(&cnt[d3.z],1); r3.w = atomicAdd(&cnt[d3.w],1); }
  if(v0) ((int4*)rank)[i0] = r0;
  if(v1) ((int4*)rank)[i1] = r1;
  if(v2) ((int4*)rank)[i2] = r2;
  if(v3) ((int4*)rank)[i3] = r3;
}

#define CHUNK 52
__global__ __launch_bounds__(1024) void scan_kernel(const int* __restrict__ deg, int* __restrict__ row_ptr){
  __shared__ int sums[1024];
  int t = threadIdx.x;
  int base = t*CHUNK;
  int4 v[13];
  int ssum = 0;
  #pragma unroll
  for(int i=0;i<13;i++){
    int idx = base + 4*i;
    if(idx + 3 < NN){
      v[i] = ((const int4*)deg)[(base>>2)+i];
    } else {
      v[i].x = (idx+0<NN)?deg[idx+0]:0; v[i].y = (idx+1<NN)?deg[idx+1]:0;
      v[i].z = (idx+2<NN)?deg[idx+2]:0; v[i].w = (idx+3<NN)?deg[idx+3]:0;
    }
    ssum += v[i].x + v[i].y + v[i].z + v[i].w;
  }
  sums[t]=ssum;
  __syncthreads();
  for(int off=1; off<1024; off<<=1){
    int vv = (t>=off) ? sums[t-off] : 0;
    __syncthreads();
    sums[t] += vv;
    __syncthreads();
  }
  int run = (t>0) ? sums[t-1] : 0;
  #pragma unroll
  for(int i=0;i<13;i++){
    int idx = base + 4*i;
    int4 o;
    o.x = run; run += v[i].x;
    o.y = run; run += v[i].y;
    o.z = run; run += v[i].z;
    o.w = run; run += v[i].w;
    if(idx + 3 < NN){
      ((int4*)row_ptr)[(base>>2)+i] = o;
    } else {
      if(idx+0<NN) row_ptr[idx+0]=o.x;
      if(idx+1<NN) row_ptr[idx+1]=o.y;
      if(idx+2<NN) row_ptr[idx+2]=o.z;
      if(idx+3<NN) row_ptr[idx+3]=o.w;
    }
  }
  if(t==1023) row_ptr[NN] = sums[1023];
}

__global__ __launch_bounds__(256) void fill_kernel(const int* __restrict__ ei,
    const int* __restrict__ row_ptr, const int* __restrict__ rank, int* __restrict__ csr_src){
  int t = blockIdx.x*256 + threadIdx.x;
  if(t < NE/4){
    int4 d  = ((const int4*)(ei + NE))[t];
    int4 sv = ((const int4*)ei)[t];
    int4 rk = ((const int4*)rank)[t];
    csr_src[row_ptr[d.x] + rk.x] = sv.x;
    csr_src[row_ptr[d.y] + rk.y] = sv.y;
    csr_src[row_ptr[d.z] + rk.z] = sv.z;
    csr_src[row_ptr[d.w] + rk.w] = sv.w;
  }
}

// ---------------- embed MLP + layer-0 PQR, 4 lanes/node ----------------
__global__ __launch_bounds__(256) void embed_pqr_kernel(
    const float* __restrict__ x,
    const float* __restrict__ W1, const float* __restrict__ b1,
    const float* __restrict__ g1, const float* __restrict__ bb1,
    const float* __restrict__ W2, const float* __restrict__ b2,
    const float* __restrict__ g2, const float* __restrict__ bb2,
    const float* __restrict__ Wm, const float* __restrict__ bm,
    const float* __restrict__ Wu, const float* __restrict__ bu,
    const float* __restrict__ fb1, const float* __restrict__ fbng, const float* __restrict__ fbnb,
    float* __restrict__ h, float* __restrict__ pre,
    float* __restrict__ P, _Float16* __restrict__ Qh, float* __restrict__ R,
    float* __restrict__ cvec)
{
  int t = blockIdx.x*256 + threadIdx.x;
  const float rs = rsqrtf(1.0f + LN_EPS);
  if(t < 64) cvec[t] = fmaf(fb1[t], fbng[t]*rs, fbnb[t]);
  int n = t >> 2, q = t & 3;
  if(n >= NN) return;
  int base = threadIdx.x & 60;
  float4 xq = ((const float4*)x)[n*4 + q];
  float xv[16];
  #pragma unroll
  for(int m=0;m<4;m++){
    xv[4*m+0]=__shfl(xq.x, base|m);
    xv[4*m+1]=__shfl(xq.y, base|m);
    xv[4*m+2]=__shfl(xq.z, base|m);
    xv[4*m+3]=__shfl(xq.w, base|m);
  }
  float a1q[16]; ld16(b1 + q*16, a1q);
  #pragma unroll
  for(int k=0;k<16;k++){
    float w[16]; ld16(W1 + k*64 + q*16, w);
    float xk = xv[k];
    #pragma unroll
    for(int j=0;j<16;j++) a1q[j] += xk * w[j];
  }
  { float g[16], b[16]; ld16(g1+q*16,g); ld16(bb1+q*16,b);
    #pragma unroll
    for(int j=0;j<16;j++) a1q[j] = gelu_f(a1q[j]*(g[j]*rs) + b[j]); }
  float hq[8]; ld8(b2 + q*8, hq);
  #pragma unroll
  for(int m=0;m<4;m++){
    #pragma unroll
    for(int kk=0;kk<16;kk++){
      float a = __shfl(a1q[kk], base|m);
      float w[8]; ld8(W2 + (m*16+kk)*32 + q*8, w);
      #pragma unroll
      for(int j=0;j<8;j++) hq[j] += a * w[j];
    }
  }
  { float g[8], b[8]; ld8(g2+q*8,g); ld8(bb2+q*8,b);
    #pragma unroll
    for(int j=0;j<8;j++) hq[j] = gelu_f(hq[j]*(g[j]*rs) + b[j]); }
  st8(h   + (size_t)n*32 + q*8, hq);
  st8(pre + (size_t)n*32 + q*8, hq);
  float apv[8], aqv[8], arv[8];
  ld8(bm+q*8, apv); ld8(bu+q*8, arv);
  #pragma unroll
  for(int j=0;j<8;j++) aqv[j]=0.f;
  #pragma unroll
  for(int m=0;m<4;m++){
    #pragma unroll
    for(int kk=0;kk<8;kk++){
      float hk = __shfl(hq[kk], base|m);
      int k = m*8+kk;
      float wm[8],wq[8],wu[8];
      ld8(Wm + k*32      + q*8, wm);
      ld8(Wm + (32+k)*32 + q*8, wq);
      ld8(Wu + k*32      + q*8, wu);
      #pragma unroll
      for(int j=0;j<8;j++){ apv[j]+=hk*wm[j]; aqv[j]+=hk*wq[j]; arv[j]+=hk*wu[j]; }
    }
  }
  st8(P + (size_t)n*32 + q*8, apv);
  st8(R + (size_t)n*32 + q*8, arv);
  half8 qo;
  #pragma unroll
  for(int k=0;k<8;k++) qo[k] = (_Float16)aqv[k];
  *(half8*)(Qh + (size_t)n*32 + q*8) = qo;
}

// -------- message+aggregate: 4 lanes per edge (slot,q), one 64B line per edge --------
__global__ __launch_bounds__(256) void msg_kernel(
    const float* __restrict__ P, const _Float16* __restrict__ Qh,
    const int* __restrict__ row_ptr, const int* __restrict__ csr_src,
    const float* __restrict__ mg, const float* __restrict__ mb,
    float* __restrict__ aggO)
{
  int tid = blockIdx.x*256 + threadIdx.x;   // grid = NN*16 exactly
  int n = tid >> 4;
  int s = tid & 15;
  int slot = s >> 2;
  int q = s & 3;
  float mgq[8], mbq[8], p8[8];
  ld8(mg + q*8, mgq); ld8(mb + q*8, mbq);
  ld8(P + (size_t)n*32 + q*8, p8);
  float agg8[8] = {0,0,0,0,0,0,0,0};
  int e0 = row_ptr[n], e1 = row_ptr[n+1];
  int e = e0 + slot;
  int src = (e < e1) ? csr_src[e] : 0;
  half8 qv = *(const half8*)(Qh + (size_t)src*32 + q*8);
  while(e < e1){
    int e2 = e + 4;
    int src2 = (e2 < e1) ? csr_src[e2] : 0;
    half8 qv2 = *(const half8*)(Qh + (size_t)src2*32 + q*8);
    float v[8];
    #pragma unroll
    for(int k=0;k<8;k++) v[k] = p8[k] + (float)qv[k];
    float ps = ((v[0]+v[1])+(v[2]+v[3])) + ((v[4]+v[5])+(v[6]+v[7]));
    ps += __shfl_xor(ps,1); ps += __shfl_xor(ps,2);
    float mean = ps * 0.03125f;
    float vs = 0.f;
    #pragma unroll
    for(int k=0;k<8;k++){ float dd = v[k]-mean; vs += dd*dd; v[k]=dd; }
    vs += __shfl_xor(vs,1); vs += __shfl_xor(vs,2);
    float rstd = rsqrtf(vs*0.03125f + LN_EPS);
    #pragma unroll
    for(int k=0;k<8;k++) agg8[k] += gelu_f(v[k]*rstd*mgq[k] + mbq[k]);
    qv = qv2; e = e2;
  }
  #pragma unroll
  for(int k=0;k<8;k++) agg8[k] += __shfl_xor(agg8[k], 4);
  #pragma unroll
  for(int k=0;k<8;k++) agg8[k] += __shfl_xor(agg8[k], 8);
  if(slot==0) st8(aggO + (size_t)n*32 + q*8, agg8);
}

// -------- update MLP + next-layer PQR, 4 lanes/node --------
__global__ __launch_bounds__(256) void upd_pqr_kernel(
    const float* __restrict__ aggI, const float* __restrict__ Rio,
    const float* __restrict__ Ub,
    const float* __restrict__ ug, const float* __restrict__ ub,
    const float* __restrict__ Wm2, const float* __restrict__ bm2,
    const float* __restrict__ Wu2, const float* __restrict__ bu2,
    float* __restrict__ h,
    float* __restrict__ P, _Float16* __restrict__ Qh, float* __restrict__ Rout)
{
  int t = blockIdx.x*256 + threadIdx.x;
  int n = t >> 2, q = t & 3;
  if(n >= NN) return;
  int base = threadIdx.x & 60;
  float aggq[8], uq[8];
  ld8(aggI + (size_t)n*32 + q*8, aggq);
  ld8(Rio  + (size_t)n*32 + q*8, uq);
  #pragma unroll
  for(int m=0;m<4;m++){
    #pragma unroll
    for(int kk=0;kk<8;kk++){
      float a = __shfl(aggq[kk], base|m);
      float w[8]; ld8(Ub + (m*8+kk)*32 + q*8, w);
      #pragma unroll
      for(int j=0;j<8;j++) uq[j] += a * w[j];
    }
  }
  float sm = ((uq[0]+uq[1])+(uq[2]+uq[3])) + ((uq[4]+uq[5])+(uq[6]+uq[7]));
  sm += __shfl_xor(sm,1); sm += __shfl_xor(sm,2);
  float mean = sm * 0.03125f;
  float vs = 0.f;
  #pragma unroll
  for(int j=0;j<8;j++){ float d = uq[j]-mean; vs += d*d; uq[j]=d; }
  vs += __shfl_xor(vs,1); vs += __shfl_xor(vs,2);
  float rstd = rsqrtf(vs*0.03125f + LN_EPS);
  float ugq[8], ubq[8], hq[8];
  ld8(ug+q*8, ugq); ld8(ub+q*8, ubq);
  ld8(h + (size_t)n*32 + q*8, hq);
  #pragma unroll
  for(int j=0;j<8;j++) hq[j] += gelu_f(uq[j]*rstd*ugq[j] + ubq[j]);
  st8(h + (size_t)n*32 + q*8, hq);
  // next-layer PQR
  float apv[8], aqv[8], arv[8];
  ld8(bm2+q*8, apv); ld8(bu2+q*8, arv);
  #pragma unroll
  for(int j=0;j<8;j++) aqv[j]=0.f;
  #pragma unroll
  for(int m=0;m<4;m++){
    #pragma unroll
    for(int kk=0;kk<8;kk++){
      float hk = __shfl(hq[kk], base|m);
      int k = m*8+kk;
      float wm[8],wq[8],wu[8];
      ld8(Wm2 + k*32      + q*8, wm);
      ld8(Wm2 + (32+k)*32 + q*8, wq);
      ld8(Wu2 + k*32      + q*8, wu);
      #pragma unroll
      for(int j=0;j<8;j++){ apv[j]+=hk*wm[j]; aqv[j]+=hk*wq[j]; arv[j]+=hk*wu[j]; }
    }
  }
  st8(P    + (size_t)n*32 + q*8, apv);
  st8(Rout + (size_t)n*32 + q*8, arv);
  half8 qo;
  #pragma unroll
  for(int k=0;k<8;k++) qo[k] = (_Float16)aqv[k];
  *(half8*)(Qh + (size_t)n*32 + q*8) = qo;
}

// -------- last update + final node matmul, 4 lanes/node, split-half fp16 y --------
__global__ __launch_bounds__(256) void upd_fin_kernel(
    const float* __restrict__ aggI, const float* __restrict__ Rio,
    const float* __restrict__ Ub,
    const float* __restrict__ ug, const float* __restrict__ ub,
    const float* __restrict__ h, const float* __restrict__ pre,
    const float* __restrict__ fW1, const float* __restrict__ fbng,
    _Float16* __restrict__ y1, _Float16* __restrict__ y2)
{
  int t = blockIdx.x*256 + threadIdx.x;
  int n = t >> 2, q = t & 3;
  if(n >= NN) return;
  int base = threadIdx.x & 60;
  const float rs = rsqrtf(1.0f + LN_EPS);
  float aggq[8], uq[8];
  ld8(aggI + (size_t)n*32 + q*8, aggq);
  ld8(Rio  + (size_t)n*32 + q*8, uq);
  #pragma unroll
  for(int m=0;m<4;m++){
    #pragma unroll
    for(int kk=0;kk<8;kk++){
      float a = __shfl(aggq[kk], base|m);
      float w[8]; ld8(Ub + (m*8+kk)*32 + q*8, w);
      #pragma unroll
      for(int j=0;j<8;j++) uq[j] += a * w[j];
    }
  }
  float sm = ((uq[0]+uq[1])+(uq[2]+uq[3])) + ((uq[4]+uq[5])+(uq[6]+uq[7]));
  sm += __shfl_xor(sm,1); sm += __shfl_xor(sm,2);
  float mean = sm * 0.03125f;
  float vs = 0.f;
  #pragma unroll
  for(int j=0;j<8;j++){ float d = uq[j]-mean; vs += d*d; uq[j]=d; }
  vs += __shfl_xor(vs,1); vs += __shfl_xor(vs,2);
  float rstd = rsqrtf(vs*0.03125f + LN_EPS);
  float ugq[8], ubq[8], hq[8], pq[8];
  ld8(ug+q*8, ugq); ld8(ub+q*8, ubq);
  ld8(h   + (size_t)n*32 + q*8, hq);
  ld8(pre + (size_t)n*32 + q*8, pq);
  #pragma unroll
  for(int j=0;j<8;j++) hq[j] += gelu_f(uq[j]*rstd*ugq[j] + ubq[j]) + pq[j];
  float acc[16];
  #pragma unroll
  for(int j=0;j<16;j++) acc[j]=0.f;
  #pragma unroll
  for(int m=0;m<4;m++){
    #pragma unroll
    for(int kk=0;kk<8;kk++){
      float hk = __shfl(hq[kk], base|m);
      float w[16]; ld16(fW1 + (m*8+kk)*64 + q*16, w);
      #pragma unroll
      for(int j=0;j<16;j++) acc[j] += hk * w[j];
    }
  }
  float fg[16]; ld16(fbng + q*16, fg);
  half8 o0, o1;
  #pragma unroll
  for(int k=0;k<8;k++){
    o0[k] = (_Float16)(acc[k]   * (fg[k]*rs));
    o1[k] = (_Float16)(acc[8+k] * (fg[8+k]*rs));
  }
  _Float16* dst = (q<2) ? (y1 + (size_t)n*32 + q*16) : (y2 + (size_t)n*32 + (q-2)*16);
  ((half8*)dst)[0] = o0; ((half8*)dst)[1] = o1;
}

// ---------------- final per-edge: 4 lanes per edge, feature-split passes ----------------
__global__ __launch_bounds__(256) void finalA_kernel(
    const _Float16* __restrict__ y, const int* __restrict__ ei,
    const float* __restrict__ cvec, const float* __restrict__ W2,
    const float* __restrict__ b2, float* __restrict__ out)
{
  int t = blockIdx.x*256 + threadIdx.x;   // grid = NE*4 exactly
  int e = t >> 2, q = t & 3;
  int s = __builtin_nontemporal_load(ei + e);
  int d = __builtin_nontemporal_load(ei + NE + e);
  half8 a8 = *(const half8*)(y + (size_t)d*32 + q*8);
  half8 c8 = *(const half8*)(y + (size_t)s*32 + q*8);
  float cq[8]; ld8(cvec + q*8, cq);
  float w[24]; ld8(W2+q*24, w); ld8(W2+q*24+8, w+8); ld8(W2+q*24+16, w+16);
  float o0=0.f,o1=0.f,o2=0.f;
  #pragma unroll
  for(int k=0;k<8;k++){
    float tt = gelu_f(((float)a8[k]-(float)c8[k]) + cq[k]);
    o0 += tt*w[3*k]; o1 += tt*w[3*k+1]; o2 += tt*w[3*k+2];
  }
  o0 += __shfl_xor(o0,1); o0 += __shfl_xor(o0,2);
  o1 += __shfl_xor(o1,1); o1 += __shfl_xor(o1,2);
  o2 += __shfl_xor(o2,1); o2 += __shfl_xor(o2,2);
  float ov = (q==0) ? o0 + b2[0] : (q==1) ? o1 + b2[1] : o2 + b2[2];
  if(q < 3) __builtin_nontemporal_store(ov, out + (size_t)e*3 + q);
}

__global__ __launch_bounds__(256) void finalB_kernel(
    const _Float16* __restrict__ y, const int* __restrict__ ei,
    const float* __restrict__ cvec, const float* __restrict__ W2,
    float* __restrict__ out)
{
  int t = blockIdx.x*256 + threadIdx.x;
  int e = t >> 2, q = t & 3;
  float prev = 0.f;
  if(q < 3) prev = __builtin_nontemporal_load(out + (size_t)e*3 + q);
  int s = __builtin_nontemporal_load(ei + e);
  int d = __builtin_nontemporal_load(ei + NE + e);
  half8 a8 = *(const half8*)(y + (size_t)d*32 + q*8);
  half8 c8 = *(const half8*)(y + (size_t)s*32 + q*8);
  float cq[8]; ld8(cvec + q*8, cq);
  float w[24]; ld8(W2+q*24, w); ld8(W2+q*24+8, w+8); ld8(W2+q*24+16, w+16);
  float o0=0.f,o1=0.f,o2=0.f;
  #pragma unroll
  for(int k=0;k<8;k++){
    float tt = gelu_f(((float)a8[k]-(float)c8[k]) + cq[k]);
    o0 += tt*w[3*k]; o1 += tt*w[3*k+1]; o2 += tt*w[3*k+2];
  }
  o0 += __shfl_xor(o0,1); o0 += __shfl_xor(o0,2);
  o1 += __shfl_xor(o1,1); o1 += __shfl_xor(o1,2);
  o2 += __shfl_xor(o2,1); o2 += __shfl_xor(o2,2);
  float ov = prev + ((q==0) ? o0 : (q==1) ? o1 : o2);
  if(q < 3) __builtin_nontemporal_store(ov, out + (size_t)e*3 + q);
}

extern "C" void kernel_launch(void* const* d_in, const int* in_sizes, int n_in,
                              void* d_out, int out_size, void* d_ws, size_t ws_size,
                              hipStream_t stream)
{
  (void)in_sizes; (void)n_in; (void)out_size; (void)ws_size;
  const float* x     = (const float*)d_in[0];
  const int*   ei    = (const int*)d_in[1];
  const float* eW1   = (const float*)d_in[2];
  const float* eb1   = (const float*)d_in[3];
  const float* ebn1g = (const float*)d_in[4];
  const float* ebn1b = (const float*)d_in[5];
  const float* eW2   = (const float*)d_in[6];
  const float* eb2   = (const float*)d_in[7];
  const float* ebn2g = (const float*)d_in[8];
  const float* ebn2b = (const float*)d_in[9];
  const float* msgW  = (const float*)d_in[10];
  const float* msgb  = (const float*)d_in[11];
  const float* msglng= (const float*)d_in[12];
  const float* msglnb= (const float*)d_in[13];
  const float* updW  = (const float*)d_in[14];
  const float* updb  = (const float*)d_in[15];
  const float* updlng= (const float*)d_in[16];
  const float* updlnb= (const float*)d_in[17];
  const float* fW1   = (const float*)d_in[18];
  const float* fb1   = (const float*)d_in[19];
  const float* fbng  = (const float*)d_in[20];
  const float* fbnb  = (const float*)d_in[21];
  const float* fW2   = (const float*)d_in[22];
  const float* fb2   = (const float*)d_in[23];
  float* out = (float*)d_out;

  // workspace: h, pre, P, R, agg (NN*32 f32 each), Qh (NN*16 f32), cvec, ints
  float* f   = (float*)d_ws;
  float* h   = f;
  float* pre = f + 1*(size_t)NN*32;
  float* P   = f + 2*(size_t)NN*32;
  float* R   = f + 3*(size_t)NN*32;
  float* agg = f + 4*(size_t)NN*32;
  _Float16* Qh = (_Float16*)(f + 5*(size_t)NN*32);   // NN*32 halves
  _Float16* y1 = (_Float16*)P;                        // NN*32 halves (P dead after msg2)
  _Float16* y2 = y1 + (size_t)NN*32;                  // NN*32 halves (still within P)
  float* cvec  = f + 5*(size_t)NN*32 + (size_t)NN*16; // 64 floats
  int* ip      = (int*)(cvec + 64);
  int* cnt     = ip;              // NN
  int* row_ptr = ip + NN;         // NN+4
  int* csr     = ip + 2*NN + 4;   // NE
  int* rank    = (int*)agg;       // NE ints, aliases agg (free until msg layer 0)

  hipMemsetAsync(cnt, 0, NN*sizeof(int), stream);
  hist_kernel<<<391, 256, 0, stream>>>(ei, cnt, rank);
  scan_kernel<<<1, 1024, 0, stream>>>(cnt, row_ptr);
  fill_kernel<<<FILL_B, 256, 0, stream>>>(ei, row_ptr, rank, csr);

  embed_pqr_kernel<<<EMB_B, 256, 0, stream>>>(x, eW1, eb1, ebn1g, ebn1b,
      eW2, eb2, ebn2g, ebn2b,
      msgW, msgb, updW, updb,
      fb1, fbng, fbnb,
      h, pre, P, Qh, R, cvec);

  for(int l=0; l<3; l++){
    msg_kernel<<<(NN*16)/256, 256, 0, stream>>>(P, Qh, row_ptr, csr,
        msglng + l*32, msglnb + l*32, agg);
    if(l < 2){
      upd_pqr_kernel<<<EMB_B, 256, 0, stream>>>(agg, R,
          updW + l*2048 + 1024, updlng + l*32, updlnb + l*32,
          msgW + (l+1)*2048, msgb + (l+1)*32,
          updW + (l+1)*2048, updb + (l+1)*32,
          h, P, Qh, R);
    } else {
      upd_fin_kernel<<<EMB_B, 256, 0, stream>>>(agg, R,
          updW + l*2048 + 1024, updlng + l*32, updlnb + l*32,
          h, pre, fW1, fbng, y1, y2);
    }
  }

  finalA_kernel<<<(NE*4)/256, 256, 0, stream>>>(y1, ei, cvec,      fW2,      fb2, out);
  finalB_kernel<<<(NE*4)/256, 256, 0, stream>>>(y2, ei, cvec + 32, fW2 + 96, out);
}

// Round 10
// 500.558 us; speedup vs baseline: 1.6006x; 1.0461x over previous
//
#include <hip/hip_runtime.h>

#define NN 50000
#define NE 1600000
#define FILL_B 1563   // ceil((NE/4)/256)
#define EMB_B  782    // ceil((NN*4)/256)
#define HIST_STRIDE 100096 // 391 blocks * 256 threads
constexpr float LN_EPS = 1e-5f;

typedef _Float16 half8 __attribute__((ext_vector_type(8)));

__device__ __forceinline__ float gelu_f(float x){
  float ax = fabsf(x) * 0.70710678118654752440f;
  float t  = __builtin_amdgcn_rcpf(fmaf(0.3275911f, ax, 1.0f));
  float e  = __expf(-ax*ax);
  float p  = t*fmaf(t, fmaf(t, fmaf(t, fmaf(t, 1.061405429f, -1.453152027f),
                                    1.421413741f), -0.284496736f), 0.254829592f);
  float er = fmaf(-p, e, 1.0f);
  return 0.5f * x * (1.0f + copysignf(er, x));
}

__device__ __forceinline__ void ld8(const float* __restrict__ p, float* r){
  float4 a=((const float4*)p)[0], b=((const float4*)p)[1];
  r[0]=a.x;r[1]=a.y;r[2]=a.z;r[3]=a.w;r[4]=b.x;r[5]=b.y;r[6]=b.z;r[7]=b.w;
}
__device__ __forceinline__ void ld16(const float* __restrict__ p, float* r){ ld8(p,r); ld8(p+8,r+8); }
__device__ __forceinline__ void st8(float* __restrict__ p, const float* r){
  float4 a,b; a.x=r[0];a.y=r[1];a.z=r[2];a.w=r[3]; b.x=r[4];b.y=r[5];b.z=r[6];b.w=r[7];
  ((float4*)p)[0]=a; ((float4*)p)[1]=b;
}

// ---------------- hist: 8-way sharded counters, shard = blockIdx&7 ----------------
// rank_packed = (shard<<20) | rank_within_shard
__global__ __launch_bounds__(256) void hist_kernel(const int* __restrict__ ei,
    int* __restrict__ cnt8, int* __restrict__ rank){
  int t = blockIdx.x*256 + threadIdx.x;
  int hi = (blockIdx.x & 7) << 20;
  int* mycnt = cnt8 + (size_t)(blockIdx.x & 7)*NN;
  int i0 = t, i1 = t + HIST_STRIDE, i2 = t + 2*HIST_STRIDE, i3 = t + 3*HIST_STRIDE;
  bool v0 = i0 < NE/4, v1 = i1 < NE/4, v2 = i2 < NE/4, v3 = i3 < NE/4;
  int4 d0 = v0 ? ((const int4*)(ei + NE))[i0] : make_int4(0,0,0,0);
  int4 d1 = v1 ? ((const int4*)(ei + NE))[i1] : make_int4(0,0,0,0);
  int4 d2 = v2 ? ((const int4*)(ei + NE))[i2] : make_int4(0,0,0,0);
  int4 d3 = v3 ? ((const int4*)(ei + NE))[i3] : make_int4(0,0,0,0);
  int4 r0, r1, r2, r3;
  if(v0){ r0.x = hi|atomicAdd(&mycnt[d0.x],1); r0.y = hi|atomicAdd(&mycnt[d0.y],1);
          r0.z = hi|atomicAdd(&mycnt[d0.z],1); r0.w = hi|atomicAdd(&mycnt[d0.w],1); }
  if(v1){ r1.x = hi|atomicAdd(&mycnt[d1.x],1); r1.y = hi|atomicAdd(&mycnt[d1.y],1);
          r1.z = hi|atomicAdd(&mycnt[d1.z],1); r1.w = hi|atomicAdd(&mycnt[d1.w],1); }
  if(v2){ r2.x = hi|atomicAdd(&mycnt[d2.x],1); r2.y = hi|atomicAdd(&mycnt[d2.y],1);
          r2.z = hi|atomicAdd(&mycnt[d2.z],1); r2.w = hi|atomicAdd(&mycnt[d2.w],1); }
  if(v3){ r3.x = hi|atomicAdd(&mycnt[d3.x],1); r3.y = hi|atomicAdd(&mycnt[d3.y],1);
          r3.z = hi|atomicAdd(&mycnt[d3.z],1); r3.w = hi|atomicAdd(&mycnt[d3.w],1); }
  if(v0) ((int4*)rank)[i0] = r0;
  if(v1) ((int4*)rank)[i1] = r1;
  if(v2) ((int4*)rank)[i2] = r2;
  if(v3) ((int4*)rank)[i3] = r3;
}

// ---------------- reduce8: per-node shard prefix (in place) + deg ----------------
__global__ __launch_bounds__(256) void reduce8_kernel(int* __restrict__ cnt8,
    int* __restrict__ deg){
  int t = blockIdx.x*256 + threadIdx.x;
  if(t >= NN/4) return;
  int4 c[8];
  #pragma unroll
  for(int x=0;x<8;x++) c[x] = ((const int4*)(cnt8 + (size_t)x*NN))[t];
  int4 run = make_int4(0,0,0,0);
  #pragma unroll
  for(int x=0;x<8;x++){
    ((int4*)(cnt8 + (size_t)x*NN))[t] = run;
    run.x += c[x].x; run.y += c[x].y; run.z += c[x].z; run.w += c[x].w;
  }
  ((int4*)deg)[t] = run;
}

#define CHUNK 52
__global__ __launch_bounds__(1024) void scan_kernel(const int* __restrict__ deg, int* __restrict__ row_ptr){
  __shared__ int sums[1024];
  int t = threadIdx.x;
  int base = t*CHUNK;
  int4 v[13];
  int ssum = 0;
  #pragma unroll
  for(int i=0;i<13;i++){
    int idx = base + 4*i;
    if(idx + 3 < NN){
      v[i] = ((const int4*)deg)[(base>>2)+i];
    } else {
      v[i].x = (idx+0<NN)?deg[idx+0]:0; v[i].y = (idx+1<NN)?deg[idx+1]:0;
      v[i].z = (idx+2<NN)?deg[idx+2]:0; v[i].w = (idx+3<NN)?deg[idx+3]:0;
    }
    ssum += v[i].x + v[i].y + v[i].z + v[i].w;
  }
  sums[t]=ssum;
  __syncthreads();
  for(int off=1; off<1024; off<<=1){
    int vv = (t>=off) ? sums[t-off] : 0;
    __syncthreads();
    sums[t] += vv;
    __syncthreads();
  }
  int run = (t>0) ? sums[t-1] : 0;
  #pragma unroll
  for(int i=0;i<13;i++){
    int idx = base + 4*i;
    int4 o;
    o.x = run; run += v[i].x;
    o.y = run; run += v[i].y;
    o.z = run; run += v[i].z;
    o.w = run; run += v[i].w;
    if(idx + 3 < NN){
      ((int4*)row_ptr)[(base>>2)+i] = o;
    } else {
      if(idx+0<NN) row_ptr[idx+0]=o.x;
      if(idx+1<NN) row_ptr[idx+1]=o.y;
      if(idx+2<NN) row_ptr[idx+2]=o.z;
      if(idx+3<NN) row_ptr[idx+3]=o.w;
    }
  }
  if(t==1023) row_ptr[NN] = sums[1023];
}

// ---------------- fused: embed+PQR0 (blocks 0..EMB_B) || fill (rest) ----------------
__global__ __launch_bounds__(256) void fill_embed_kernel(
    const int* __restrict__ ei, const int* __restrict__ row_ptr,
    const int* __restrict__ rank, const int* __restrict__ offs8,
    int* __restrict__ csr,
    const float* __restrict__ x,
    const float* __restrict__ W1, const float* __restrict__ b1,
    const float* __restrict__ g1, const float* __restrict__ bb1,
    const float* __restrict__ W2, const float* __restrict__ b2,
    const float* __restrict__ g2, const float* __restrict__ bb2,
    const float* __restrict__ Wm, const float* __restrict__ bm,
    const float* __restrict__ Wu, const float* __restrict__ bu,
    const float* __restrict__ fb1, const float* __restrict__ fbng, const float* __restrict__ fbnb,
    float* __restrict__ h, float* __restrict__ pre,
    float* __restrict__ P, _Float16* __restrict__ Qh, float* __restrict__ R,
    float* __restrict__ cvec)
{
  if(blockIdx.x >= EMB_B){
    int t = (blockIdx.x - EMB_B)*256 + threadIdx.x;
    if(t < NE/4){
      int4 d  = ((const int4*)(ei + NE))[t];
      int4 sv = ((const int4*)ei)[t];
      int4 rk = ((const int4*)rank)[t];
      csr[row_ptr[d.x] + offs8[(size_t)((unsigned)rk.x>>20)*NN + d.x] + (rk.x & 0xFFFFF)] = sv.x;
      csr[row_ptr[d.y] + offs8[(size_t)((unsigned)rk.y>>20)*NN + d.y] + (rk.y & 0xFFFFF)] = sv.y;
      csr[row_ptr[d.z] + offs8[(size_t)((unsigned)rk.z>>20)*NN + d.z] + (rk.z & 0xFFFFF)] = sv.z;
      csr[row_ptr[d.w] + offs8[(size_t)((unsigned)rk.w>>20)*NN + d.w] + (rk.w & 0xFFFFF)] = sv.w;
    }
    return;
  }
  int t = blockIdx.x*256 + threadIdx.x;
  const float rs = rsqrtf(1.0f + LN_EPS);
  if(t < 64) cvec[t] = fmaf(fb1[t], fbng[t]*rs, fbnb[t]);
  int n = t >> 2, q = t & 3;
  if(n >= NN) return;
  int base = threadIdx.x & 60;
  float4 xq = ((const float4*)x)[n*4 + q];
  float xv[16];
  #pragma unroll
  for(int m=0;m<4;m++){
    xv[4*m+0]=__shfl(xq.x, base|m);
    xv[4*m+1]=__shfl(xq.y, base|m);
    xv[4*m+2]=__shfl(xq.z, base|m);
    xv[4*m+3]=__shfl(xq.w, base|m);
  }
  float a1q[16]; ld16(b1 + q*16, a1q);
  #pragma unroll
  for(int k=0;k<16;k++){
    float w[16]; ld16(W1 + k*64 + q*16, w);
    float xk = xv[k];
    #pragma unroll
    for(int j=0;j<16;j++) a1q[j] += xk * w[j];
  }
  { float g[16], b[16]; ld16(g1+q*16,g); ld16(bb1+q*16,b);
    #pragma unroll
    for(int j=0;j<16;j++) a1q[j] = gelu_f(a1q[j]*(g[j]*rs) + b[j]); }
  float hq[8]; ld8(b2 + q*8, hq);
  #pragma unroll
  for(int m=0;m<4;m++){
    #pragma unroll
    for(int kk=0;kk<16;kk++){
      float a = __shfl(a1q[kk], base|m);
      float w[8]; ld8(W2 + (m*16+kk)*32 + q*8, w);
      #pragma unroll
      for(int j=0;j<8;j++) hq[j] += a * w[j];
    }
  }
  { float g[8], b[8]; ld8(g2+q*8,g); ld8(bb2+q*8,b);
    #pragma unroll
    for(int j=0;j<8;j++) hq[j] = gelu_f(hq[j]*(g[j]*rs) + b[j]); }
  st8(h   + (size_t)n*32 + q*8, hq);
  st8(pre + (size_t)n*32 + q*8, hq);
  float apv[8], aqv[8], arv[8];
  ld8(bm+q*8, apv); ld8(bu+q*8, arv);
  #pragma unroll
  for(int j=0;j<8;j++) aqv[j]=0.f;
  #pragma unroll
  for(int m=0;m<4;m++){
    #pragma unroll
    for(int kk=0;kk<8;kk++){
      float hk = __shfl(hq[kk], base|m);
      int k = m*8+kk;
      float wm[8],wq[8],wu[8];
      ld8(Wm + k*32      + q*8, wm);
      ld8(Wm + (32+k)*32 + q*8, wq);
      ld8(Wu + k*32      + q*8, wu);
      #pragma unroll
      for(int j=0;j<8;j++){ apv[j]+=hk*wm[j]; aqv[j]+=hk*wq[j]; arv[j]+=hk*wu[j]; }
    }
  }
  st8(P + (size_t)n*32 + q*8, apv);
  st8(R + (size_t)n*32 + q*8, arv);
  half8 qo;
  #pragma unroll
  for(int k=0;k<8;k++) qo[k] = (_Float16)aqv[k];
  *(half8*)(Qh + (size_t)n*32 + q*8) = qo;
}

// -------- message+aggregate: 4 lanes per edge (slot,q), one 64B line per edge --------
__global__ __launch_bounds__(256) void msg_kernel(
    const float* __restrict__ P, const _Float16* __restrict__ Qh,
    const int* __restrict__ row_ptr, const int* __restrict__ csr_src,
    const float* __restrict__ mg, const float* __restrict__ mb,
    float* __restrict__ aggO)
{
  int tid = blockIdx.x*256 + threadIdx.x;   // grid = NN*16 exactly
  int n = tid >> 4;
  int s = tid & 15;
  int slot = s >> 2;
  int q = s & 3;
  float mgq[8], mbq[8], p8[8];
  ld8(mg + q*8, mgq); ld8(mb + q*8, mbq);
  ld8(P + (size_t)n*32 + q*8, p8);
  float agg8[8] = {0,0,0,0,0,0,0,0};
  int e0 = row_ptr[n], e1 = row_ptr[n+1];
  int e = e0 + slot;
  int src = (e < e1) ? csr_src[e] : 0;
  half8 qv = *(const half8*)(Qh + (size_t)src*32 + q*8);
  while(e < e1){
    int e2 = e + 4;
    int src2 = (e2 < e1) ? csr_src[e2] : 0;
    half8 qv2 = *(const half8*)(Qh + (size_t)src2*32 + q*8);
    float v[8];
    #pragma unroll
    for(int k=0;k<8;k++) v[k] = p8[k] + (float)qv[k];
    float ps = ((v[0]+v[1])+(v[2]+v[3])) + ((v[4]+v[5])+(v[6]+v[7]));
    ps += __shfl_xor(ps,1); ps += __shfl_xor(ps,2);
    float mean = ps * 0.03125f;
    float vs = 0.f;
    #pragma unroll
    for(int k=0;k<8;k++){ float dd = v[k]-mean; vs += dd*dd; v[k]=dd; }
    vs += __shfl_xor(vs,1); vs += __shfl_xor(vs,2);
    float rstd = rsqrtf(vs*0.03125f + LN_EPS);
    #pragma unroll
    for(int k=0;k<8;k++) agg8[k] += gelu_f(v[k]*rstd*mgq[k] + mbq[k]);
    qv = qv2; e = e2;
  }
  #pragma unroll
  for(int k=0;k<8;k++) agg8[k] += __shfl_xor(agg8[k], 4);
  #pragma unroll
  for(int k=0;k<8;k++) agg8[k] += __shfl_xor(agg8[k], 8);
  if(slot==0) st8(aggO + (size_t)n*32 + q*8, agg8);
}

// -------- update MLP + next-layer PQR, 4 lanes/node --------
__global__ __launch_bounds__(256) void upd_pqr_kernel(
    const float* __restrict__ aggI, const float* __restrict__ Rio,
    const float* __restrict__ Ub,
    const float* __restrict__ ug, const float* __restrict__ ub,
    const float* __restrict__ Wm2, const float* __restrict__ bm2,
    const float* __restrict__ Wu2, const float* __restrict__ bu2,
    float* __restrict__ h,
    float* __restrict__ P, _Float16* __restrict__ Qh, float* __restrict__ Rout)
{
  int t = blockIdx.x*256 + threadIdx.x;
  int n = t >> 2, q = t & 3;
  if(n >= NN) return;
  int base = threadIdx.x & 60;
  float aggq[8], uq[8];
  ld8(aggI + (size_t)n*32 + q*8, aggq);
  ld8(Rio  + (size_t)n*32 + q*8, uq);
  #pragma unroll
  for(int m=0;m<4;m++){
    #pragma unroll
    for(int kk=0;kk<8;kk++){
      float a = __shfl(aggq[kk], base|m);
      float w[8]; ld8(Ub + (m*8+kk)*32 + q*8, w);
      #pragma unroll
      for(int j=0;j<8;j++) uq[j] += a * w[j];
    }
  }
  float sm = ((uq[0]+uq[1])+(uq[2]+uq[3])) + ((uq[4]+uq[5])+(uq[6]+uq[7]));
  sm += __shfl_xor(sm,1); sm += __shfl_xor(sm,2);
  float mean = sm * 0.03125f;
  float vs = 0.f;
  #pragma unroll
  for(int j=0;j<8;j++){ float d = uq[j]-mean; vs += d*d; uq[j]=d; }
  vs += __shfl_xor(vs,1); vs += __shfl_xor(vs,2);
  float rstd = rsqrtf(vs*0.03125f + LN_EPS);
  float ugq[8], ubq[8], hq[8];
  ld8(ug+q*8, ugq); ld8(ub+q*8, ubq);
  ld8(h + (size_t)n*32 + q*8, hq);
  #pragma unroll
  for(int j=0;j<8;j++) hq[j] += gelu_f(uq[j]*rstd*ugq[j] + ubq[j]);
  st8(h + (size_t)n*32 + q*8, hq);
  // next-layer PQR
  float apv[8], aqv[8], arv[8];
  ld8(bm2+q*8, apv); ld8(bu2+q*8, arv);
  #pragma unroll
  for(int j=0;j<8;j++) aqv[j]=0.f;
  #pragma unroll
  for(int m=0;m<4;m++){
    #pragma unroll
    for(int kk=0;kk<8;kk++){
      float hk = __shfl(hq[kk], base|m);
      int k = m*8+kk;
      float wm[8],wq[8],wu[8];
      ld8(Wm2 + k*32      + q*8, wm);
      ld8(Wm2 + (32+k)*32 + q*8, wq);
      ld8(Wu2 + k*32      + q*8, wu);
      #pragma unroll
      for(int j=0;j<8;j++){ apv[j]+=hk*wm[j]; aqv[j]+=hk*wq[j]; arv[j]+=hk*wu[j]; }
    }
  }
  st8(P    + (size_t)n*32 + q*8, apv);
  st8(Rout + (size_t)n*32 + q*8, arv);
  half8 qo;
  #pragma unroll
  for(int k=0;k<8;k++) qo[k] = (_Float16)aqv[k];
  *(half8*)(Qh + (size_t)n*32 + q*8) = qo;
}

// -------- last update + final node matmul, 4 lanes/node, split-half fp16 y --------
__global__ __launch_bounds__(256) void upd_fin_kernel(
    const float* __restrict__ aggI, const float* __restrict__ Rio,
    const float* __restrict__ Ub,
    const float* __restrict__ ug, const float* __restrict__ ub,
    const float* __restrict__ h, const float* __restrict__ pre,
    const float* __restrict__ fW1, const float* __restrict__ fbng,
    _Float16* __restrict__ y1, _Float16* __restrict__ y2)
{
  int t = blockIdx.x*256 + threadIdx.x;
  int n = t >> 2, q = t & 3;
  if(n >= NN) return;
  int base = threadIdx.x & 60;
  const float rs = rsqrtf(1.0f + LN_EPS);
  float aggq[8], uq[8];
  ld8(aggI + (size_t)n*32 + q*8, aggq);
  ld8(Rio  + (size_t)n*32 + q*8, uq);
  #pragma unroll
  for(int m=0;m<4;m++){
    #pragma unroll
    for(int kk=0;kk<8;kk++){
      float a = __shfl(aggq[kk], base|m);
      float w[8]; ld8(Ub + (m*8+kk)*32 + q*8, w);
      #pragma unroll
      for(int j=0;j<8;j++) uq[j] += a * w[j];
    }
  }
  float sm = ((uq[0]+uq[1])+(uq[2]+uq[3])) + ((uq[4]+uq[5])+(uq[6]+uq[7]));
  sm += __shfl_xor(sm,1); sm += __shfl_xor(sm,2);
  float mean = sm * 0.03125f;
  float vs = 0.f;
  #pragma unroll
  for(int j=0;j<8;j++){ float d = uq[j]-mean; vs += d*d; uq[j]=d; }
  vs += __shfl_xor(vs,1); vs += __shfl_xor(vs,2);
  float rstd = rsqrtf(vs*0.03125f + LN_EPS);
  float ugq[8], ubq[8], hq[8], pq[8];
  ld8(ug+q*8, ugq); ld8(ub+q*8, ubq);
  ld8(h   + (size_t)n*32 + q*8, hq);
  ld8(pre + (size_t)n*32 + q*8, pq);
  #pragma unroll
  for(int j=0;j<8;j++) hq[j] += gelu_f(uq[j]*rstd*ugq[j] + ubq[j]) + pq[j];
  float acc[16];
  #pragma unroll
  for(int j=0;j<16;j++) acc[j]=0.f;
  #pragma unroll
  for(int m=0;m<4;m++){
    #pragma unroll
    for(int kk=0;kk<8;kk++){
      float hk = __shfl(hq[kk], base|m);
      float w[16]; ld16(fW1 + (m*8+kk)*64 + q*16, w);
      #pragma unroll
      for(int j=0;j<16;j++) acc[j] += hk * w[j];
    }
  }
  float fg[16]; ld16(fbng + q*16, fg);
  half8 o0, o1;
  #pragma unroll
  for(int k=0;k<8;k++){
    o0[k] = (_Float16)(acc[k]   * (fg[k]*rs));
    o1[k] = (_Float16)(acc[8+k] * (fg[8+k]*rs));
  }
  _Float16* dst = (q<2) ? (y1 + (size_t)n*32 + q*16) : (y2 + (size_t)n*32 + (q-2)*16);
  ((half8*)dst)[0] = o0; ((half8*)dst)[1] = o1;
}

// ---------------- final per-edge: 4 lanes per edge, feature-split passes ----------------
__global__ __launch_bounds__(256) void finalA_kernel(
    const _Float16* __restrict__ y, const int* __restrict__ ei,
    const float* __restrict__ cvec, const float* __restrict__ W2,
    const float* __restrict__ b2, float* __restrict__ out)
{
  int t = blockIdx.x*256 + threadIdx.x;   // grid = NE*4 exactly
  int e = t >> 2, q = t & 3;
  int s = __builtin_nontemporal_load(ei + e);
  int d = __builtin_nontemporal_load(ei + NE + e);
  half8 a8 = *(const half8*)(y + (size_t)d*32 + q*8);
  half8 c8 = *(const half8*)(y + (size_t)s*32 + q*8);
  float cq[8]; ld8(cvec + q*8, cq);
  float w[24]; ld8(W2+q*24, w); ld8(W2+q*24+8, w+8); ld8(W2+q*24+16, w+16);
  float o0=0.f,o1=0.f,o2=0.f;
  #pragma unroll
  for(int k=0;k<8;k++){
    float tt = gelu_f(((float)a8[k]-(float)c8[k]) + cq[k]);
    o0 += tt*w[3*k]; o1 += tt*w[3*k+1]; o2 += tt*w[3*k+2];
  }
  o0 += __shfl_xor(o0,1); o0 += __shfl_xor(o0,2);
  o1 += __shfl_xor(o1,1); o1 += __shfl_xor(o1,2);
  o2 += __shfl_xor(o2,1); o2 += __shfl_xor(o2,2);
  float ov = (q==0) ? o0 + b2[0] : (q==1) ? o1 + b2[1] : o2 + b2[2];
  if(q < 3) __builtin_nontemporal_store(ov, out + (size_t)e*3 + q);
}

__global__ __launch_bounds__(256) void finalB_kernel(
    const _Float16* __restrict__ y, const int* __restrict__ ei,
    const float* __restrict__ cvec, const float* __restrict__ W2,
    float* __restrict__ out)
{
  int t = blockIdx.x*256 + threadIdx.x;
  int e = t >> 2, q = t & 3;
  float prev = 0.f;
  if(q < 3) prev = __builtin_nontemporal_load(out + (size_t)e*3 + q);
  int s = __builtin_nontemporal_load(ei + e);
  int d = __builtin_nontemporal_load(ei + NE + e);
  half8 a8 = *(const half8*)(y + (size_t)d*32 + q*8);
  half8 c8 = *(const half8*)(y + (size_t)s*32 + q*8);
  float cq[8]; ld8(cvec + q*8, cq);
  float w[24]; ld8(W2+q*24, w); ld8(W2+q*24+8, w+8); ld8(W2+q*24+16, w+16);
  float o0=0.f,o1=0.f,o2=0.f;
  #pragma unroll
  for(int k=0;k<8;k++){
    float tt = gelu_f(((float)a8[k]-(float)c8[k]) + cq[k]);
    o0 += tt*w[3*k]; o1 += tt*w[3*k+1]; o2 += tt*w[3*k+2];
  }
  o0 += __shfl_xor(o0,1); o0 += __shfl_xor(o0,2);
  o1 += __shfl_xor(o1,1); o1 += __shfl_xor(o1,2);
  o2 += __shfl_xor(o2,1); o2 += __shfl_xor(o2,2);
  float ov = prev + ((q==0) ? o0 : (q==1) ? o1 : o2);
  if(q < 3) __builtin_nontemporal_store(ov, out + (size_t)e*3 + q);
}

extern "C" void kernel_launch(void* const* d_in, const int* in_sizes, int n_in,
                              void* d_out, int out_size, void* d_ws, size_t ws_size,
                              hipStream_t stream)
{
  (void)in_sizes; (void)n_in; (void)out_size; (void)ws_size;
  const float* x     = (const float*)d_in[0];
  const int*   ei    = (const int*)d_in[1];
  const float* eW1   = (const float*)d_in[2];
  const float* eb1   = (const float*)d_in[3];
  const float* ebn1g = (const float*)d_in[4];
  const float* ebn1b = (const float*)d_in[5];
  const float* eW2   = (const float*)d_in[6];
  const float* eb2   = (const float*)d_in[7];
  const float* ebn2g = (const float*)d_in[8];
  const float* ebn2b = (const float*)d_in[9];
  const float* msgW  = (const float*)d_in[10];
  const float* msgb  = (const float*)d_in[11];
  const float* msglng= (const float*)d_in[12];
  const float* msglnb= (const float*)d_in[13];
  const float* updW  = (const float*)d_in[14];
  const float* updb  = (const float*)d_in[15];
  const float* updlng= (const float*)d_in[16];
  const float* updlnb= (const float*)d_in[17];
  const float* fW1   = (const float*)d_in[18];
  const float* fb1   = (const float*)d_in[19];
  const float* fbng  = (const float*)d_in[20];
  const float* fbnb  = (const float*)d_in[21];
  const float* fW2   = (const float*)d_in[22];
  const float* fb2   = (const float*)d_in[23];
  float* out = (float*)d_out;

  // workspace: h, pre, P, R, agg (NN*32 f32 each), Qh (NN*16 f32), cvec, ints
  float* f   = (float*)d_ws;
  float* h   = f;
  float* pre = f + 1*(size_t)NN*32;
  float* P   = f + 2*(size_t)NN*32;
  float* R   = f + 3*(size_t)NN*32;
  float* agg = f + 4*(size_t)NN*32;
  _Float16* Qh = (_Float16*)(f + 5*(size_t)NN*32);   // NN*32 halves
  _Float16* y1 = (_Float16*)P;                        // NN*32 halves (P dead after msg2)
  _Float16* y2 = y1 + (size_t)NN*32;                  // NN*32 halves (still within P)
  float* cvec  = f + 5*(size_t)NN*32 + (size_t)NN*16; // 64 floats
  int* ip      = (int*)(cvec + 64);
  int* cnt8    = ip;                  // 8*NN (becomes offs8 after reduce8)
  int* deg     = ip + 8*NN;           // NN
  int* row_ptr = ip + 9*NN;           // NN+4
  int* csr     = ip + 10*NN + 4;      // NE
  int* rank    = (int*)agg;           // NE ints, aliases agg (free until msg layer 0)

  hipMemsetAsync(cnt8, 0, (size_t)8*NN*sizeof(int), stream);
  hist_kernel<<<391, 256, 0, stream>>>(ei, cnt8, rank);
  reduce8_kernel<<<(NN/4+255)/256, 256, 0, stream>>>(cnt8, deg);
  scan_kernel<<<1, 1024, 0, stream>>>(deg, row_ptr);
  fill_embed_kernel<<<EMB_B + FILL_B, 256, 0, stream>>>(ei, row_ptr, rank, cnt8, csr,
      x, eW1, eb1, ebn1g, ebn1b,
      eW2, eb2, ebn2g, ebn2b,
      msgW, msgb, updW, updb,
      fb1, fbng, fbnb,
      h, pre, P, Qh, R, cvec);

  for(int l=0; l<3; l++){
    msg_kernel<<<(NN*16)/256, 256, 0, stream>>>(P, Qh, row_ptr, csr,
        msglng + l*32, msglnb + l*32, agg);
    if(l < 2){
      upd_pqr_kernel<<<EMB_B, 256, 0, stream>>>(agg, R,
          updW + l*2048 + 1024, updlng + l*32, updlnb + l*32,
          msgW + (l+1)*2048, msgb + (l+1)*32,
          updW + (l+1)*2048, updb + (l+1)*32,
          h, P, Qh, R);
    } else {
      upd_fin_kernel<<<EMB_B, 256, 0, stream>>>(agg, R,
          updW + l*2048 + 1024, updlng + l*32, updlnb + l*32,
          h, pre, fW1, fbng, y1, y2);
    }
  }

  finalA_kernel<<<(NE*4)/256, 256, 0, stream>>>(y1, ei, cvec,      fW2,      fb2, out);
  finalB_kernel<<<(NE*4)/256, 256, 0, stream>>>(y2, ei, cvec + 32, fW2 + 96, out);
}

// Round 11
// 488.919 us; speedup vs baseline: 1.6387x; 1.0238x over previous
//
#include <hip/hip_runtime.h>

#define NN 50000
#define NE 1600000
#define FILL_B 1563   // ceil((NE/4)/256)
#define EMB_B  782    // ceil((NN*4)/256)
#define HIST_STRIDE 100096 // 391 blocks * 256 threads
constexpr float LN_EPS = 1e-5f;

typedef _Float16 half8 __attribute__((ext_vector_type(8)));

__device__ __forceinline__ float gelu_f(float x){
  float ax = fabsf(x) * 0.70710678118654752440f;
  float t  = __builtin_amdgcn_rcpf(fmaf(0.3275911f, ax, 1.0f));
  float e  = __expf(-ax*ax);
  float p  = t*fmaf(t, fmaf(t, fmaf(t, fmaf(t, 1.061405429f, -1.453152027f),
                                    1.421413741f), -0.284496736f), 0.254829592f);
  float er = fmaf(-p, e, 1.0f);
  return 0.5f * x * (1.0f + copysignf(er, x));
}

__device__ __forceinline__ void ld8(const float* __restrict__ p, float* r){
  float4 a=((const float4*)p)[0], b=((const float4*)p)[1];
  r[0]=a.x;r[1]=a.y;r[2]=a.z;r[3]=a.w;r[4]=b.x;r[5]=b.y;r[6]=b.z;r[7]=b.w;
}
__device__ __forceinline__ void ld16(const float* __restrict__ p, float* r){ ld8(p,r); ld8(p+8,r+8); }
__device__ __forceinline__ void st8(float* __restrict__ p, const float* r){
  float4 a,b; a.x=r[0];a.y=r[1];a.z=r[2];a.w=r[3]; b.x=r[4];b.y=r[5];b.z=r[6];b.w=r[7];
  ((float4*)p)[0]=a; ((float4*)p)[1]=b;
}

// ---------------- hist: 16-way sharded counters, shard = blockIdx&15 ----------------
// rank_packed = (shard<<20) | rank_within_shard
__global__ __launch_bounds__(256) void hist_kernel(const int* __restrict__ ei,
    int* __restrict__ cnt16, int* __restrict__ rank){
  int t = blockIdx.x*256 + threadIdx.x;
  int hi = (blockIdx.x & 15) << 20;
  int* mycnt = cnt16 + (size_t)(blockIdx.x & 15)*NN;
  int i0 = t, i1 = t + HIST_STRIDE, i2 = t + 2*HIST_STRIDE, i3 = t + 3*HIST_STRIDE;
  bool v0 = i0 < NE/4, v1 = i1 < NE/4, v2 = i2 < NE/4, v3 = i3 < NE/4;
  int4 d0 = v0 ? ((const int4*)(ei + NE))[i0] : make_int4(0,0,0,0);
  int4 d1 = v1 ? ((const int4*)(ei + NE))[i1] : make_int4(0,0,0,0);
  int4 d2 = v2 ? ((const int4*)(ei + NE))[i2] : make_int4(0,0,0,0);
  int4 d3 = v3 ? ((const int4*)(ei + NE))[i3] : make_int4(0,0,0,0);
  int4 r0, r1, r2, r3;
  if(v0){ r0.x = hi|atomicAdd(&mycnt[d0.x],1); r0.y = hi|atomicAdd(&mycnt[d0.y],1);
          r0.z = hi|atomicAdd(&mycnt[d0.z],1); r0.w = hi|atomicAdd(&mycnt[d0.w],1); }
  if(v1){ r1.x = hi|atomicAdd(&mycnt[d1.x],1); r1.y = hi|atomicAdd(&mycnt[d1.y],1);
          r1.z = hi|atomicAdd(&mycnt[d1.z],1); r1.w = hi|atomicAdd(&mycnt[d1.w],1); }
  if(v2){ r2.x = hi|atomicAdd(&mycnt[d2.x],1); r2.y = hi|atomicAdd(&mycnt[d2.y],1);
          r2.z = hi|atomicAdd(&mycnt[d2.z],1); r2.w = hi|atomicAdd(&mycnt[d2.w],1); }
  if(v3){ r3.x = hi|atomicAdd(&mycnt[d3.x],1); r3.y = hi|atomicAdd(&mycnt[d3.y],1);
          r3.z = hi|atomicAdd(&mycnt[d3.z],1); r3.w = hi|atomicAdd(&mycnt[d3.w],1); }
  if(v0) ((int4*)rank)[i0] = r0;
  if(v1) ((int4*)rank)[i1] = r1;
  if(v2) ((int4*)rank)[i2] = r2;
  if(v3) ((int4*)rank)[i3] = r3;
}

// ---------------- reduce16: per-node shard prefix (in place) + deg ----------------
__global__ __launch_bounds__(256) void reduce16_kernel(int* __restrict__ cnt16,
    int* __restrict__ deg){
  int t = blockIdx.x*256 + threadIdx.x;
  if(t >= NN/4) return;
  int4 run = make_int4(0,0,0,0);
  #pragma unroll
  for(int x=0;x<16;x++){
    int4 c = ((const int4*)(cnt16 + (size_t)x*NN))[t];
    ((int4*)(cnt16 + (size_t)x*NN))[t] = run;
    run.x += c.x; run.y += c.y; run.z += c.z; run.w += c.w;
  }
  ((int4*)deg)[t] = run;
}

#define CHUNK 52
__global__ __launch_bounds__(1024) void scan_kernel(const int* __restrict__ deg, int* __restrict__ row_ptr){
  __shared__ int sums[1024];
  int t = threadIdx.x;
  int base = t*CHUNK;
  int4 v[13];
  int ssum = 0;
  #pragma unroll
  for(int i=0;i<13;i++){
    int idx = base + 4*i;
    if(idx + 3 < NN){
      v[i] = ((const int4*)deg)[(base>>2)+i];
    } else {
      v[i].x = (idx+0<NN)?deg[idx+0]:0; v[i].y = (idx+1<NN)?deg[idx+1]:0;
      v[i].z = (idx+2<NN)?deg[idx+2]:0; v[i].w = (idx+3<NN)?deg[idx+3]:0;
    }
    ssum += v[i].x + v[i].y + v[i].z + v[i].w;
  }
  sums[t]=ssum;
  __syncthreads();
  for(int off=1; off<1024; off<<=1){
    int vv = (t>=off) ? sums[t-off] : 0;
    __syncthreads();
    sums[t] += vv;
    __syncthreads();
  }
  int run = (t>0) ? sums[t-1] : 0;
  #pragma unroll
  for(int i=0;i<13;i++){
    int idx = base + 4*i;
    int4 o;
    o.x = run; run += v[i].x;
    o.y = run; run += v[i].y;
    o.z = run; run += v[i].z;
    o.w = run; run += v[i].w;
    if(idx + 3 < NN){
      ((int4*)row_ptr)[(base>>2)+i] = o;
    } else {
      if(idx+0<NN) row_ptr[idx+0]=o.x;
      if(idx+1<NN) row_ptr[idx+1]=o.y;
      if(idx+2<NN) row_ptr[idx+2]=o.z;
      if(idx+3<NN) row_ptr[idx+3]=o.w;
    }
  }
  if(t==1023) row_ptr[NN] = sums[1023];
}

// ---------------- fused: embed+PQR0 (blocks 0..EMB_B) || fill (rest) ----------------
__global__ __launch_bounds__(256) void fill_embed_kernel(
    const int* __restrict__ ei, const int* __restrict__ row_ptr,
    const int* __restrict__ rank, const int* __restrict__ offs16,
    int* __restrict__ csr,
    const float* __restrict__ x,
    const float* __restrict__ W1, const float* __restrict__ b1,
    const float* __restrict__ g1, const float* __restrict__ bb1,
    const float* __restrict__ W2, const float* __restrict__ b2,
    const float* __restrict__ g2, const float* __restrict__ bb2,
    const float* __restrict__ Wm, const float* __restrict__ bm,
    const float* __restrict__ Wu, const float* __restrict__ bu,
    const float* __restrict__ fb1, const float* __restrict__ fbng, const float* __restrict__ fbnb,
    float* __restrict__ h, float* __restrict__ pre,
    float* __restrict__ P, _Float16* __restrict__ Qh, float* __restrict__ R,
    float* __restrict__ cvec)
{
  if(blockIdx.x >= EMB_B){
    int t = (blockIdx.x - EMB_B)*256 + threadIdx.x;
    if(t < NE/4){
      int4 d  = ((const int4*)(ei + NE))[t];
      int4 sv = ((const int4*)ei)[t];
      int4 rk = ((const int4*)rank)[t];
      csr[row_ptr[d.x] + offs16[(size_t)((unsigned)rk.x>>20)*NN + d.x] + (rk.x & 0xFFFFF)] = sv.x;
      csr[row_ptr[d.y] + offs16[(size_t)((unsigned)rk.y>>20)*NN + d.y] + (rk.y & 0xFFFFF)] = sv.y;
      csr[row_ptr[d.z] + offs16[(size_t)((unsigned)rk.z>>20)*NN + d.z] + (rk.z & 0xFFFFF)] = sv.z;
      csr[row_ptr[d.w] + offs16[(size_t)((unsigned)rk.w>>20)*NN + d.w] + (rk.w & 0xFFFFF)] = sv.w;
    }
    return;
  }
  int t = blockIdx.x*256 + threadIdx.x;
  const float rs = rsqrtf(1.0f + LN_EPS);
  if(t < 64) cvec[t] = fmaf(fb1[t], fbng[t]*rs, fbnb[t]);
  int n = t >> 2, q = t & 3;
  if(n >= NN) return;
  int base = threadIdx.x & 60;
  float4 xq = ((const float4*)x)[n*4 + q];
  float xv[16];
  #pragma unroll
  for(int m=0;m<4;m++){
    xv[4*m+0]=__shfl(xq.x, base|m);
    xv[4*m+1]=__shfl(xq.y, base|m);
    xv[4*m+2]=__shfl(xq.z, base|m);
    xv[4*m+3]=__shfl(xq.w, base|m);
  }
  float a1q[16]; ld16(b1 + q*16, a1q);
  #pragma unroll
  for(int k=0;k<16;k++){
    float w[16]; ld16(W1 + k*64 + q*16, w);
    float xk = xv[k];
    #pragma unroll
    for(int j=0;j<16;j++) a1q[j] += xk * w[j];
  }
  { float g[16], b[16]; ld16(g1+q*16,g); ld16(bb1+q*16,b);
    #pragma unroll
    for(int j=0;j<16;j++) a1q[j] = gelu_f(a1q[j]*(g[j]*rs) + b[j]); }
  float hq[8]; ld8(b2 + q*8, hq);
  #pragma unroll
  for(int m=0;m<4;m++){
    #pragma unroll
    for(int kk=0;kk<16;kk++){
      float a = __shfl(a1q[kk], base|m);
      float w[8]; ld8(W2 + (m*16+kk)*32 + q*8, w);
      #pragma unroll
      for(int j=0;j<8;j++) hq[j] += a * w[j];
    }
  }
  { float g[8], b[8]; ld8(g2+q*8,g); ld8(bb2+q*8,b);
    #pragma unroll
    for(int j=0;j<8;j++) hq[j] = gelu_f(hq[j]*(g[j]*rs) + b[j]); }
  st8(h   + (size_t)n*32 + q*8, hq);
  st8(pre + (size_t)n*32 + q*8, hq);
  float apv[8], aqv[8], arv[8];
  ld8(bm+q*8, apv); ld8(bu+q*8, arv);
  #pragma unroll
  for(int j=0;j<8;j++) aqv[j]=0.f;
  #pragma unroll
  for(int m=0;m<4;m++){
    #pragma unroll
    for(int kk=0;kk<8;kk++){
      float hk = __shfl(hq[kk], base|m);
      int k = m*8+kk;
      float wm[8],wq[8],wu[8];
      ld8(Wm + k*32      + q*8, wm);
      ld8(Wm + (32+k)*32 + q*8, wq);
      ld8(Wu + k*32      + q*8, wu);
      #pragma unroll
      for(int j=0;j<8;j++){ apv[j]+=hk*wm[j]; aqv[j]+=hk*wq[j]; arv[j]+=hk*wu[j]; }
    }
  }
  st8(P + (size_t)n*32 + q*8, apv);
  st8(R + (size_t)n*32 + q*8, arv);
  half8 qo;
  #pragma unroll
  for(int k=0;k<8;k++) qo[k] = (_Float16)aqv[k];
  *(half8*)(Qh + (size_t)n*32 + q*8) = qo;
}

// -------- message+aggregate: 8 slots x 4q = 32 lanes/node --------
__global__ __launch_bounds__(256) void msg_kernel(
    const float* __restrict__ P, const _Float16* __restrict__ Qh,
    const int* __restrict__ row_ptr, const int* __restrict__ csr_src,
    const float* __restrict__ mg, const float* __restrict__ mb,
    float* __restrict__ aggO)
{
  int tid = blockIdx.x*256 + threadIdx.x;   // grid = NN*32 exactly
  int n = tid >> 5;
  int s = tid & 31;
  int slot = s >> 2;   // 0..7
  int q = s & 3;
  float mgq[8], mbq[8], p8[8];
  ld8(mg + q*8, mgq); ld8(mb + q*8, mbq);
  ld8(P + (size_t)n*32 + q*8, p8);
  float agg8[8] = {0,0,0,0,0,0,0,0};
  int e0 = row_ptr[n], e1 = row_ptr[n+1];
  int e = e0 + slot;
  int src = (e < e1) ? csr_src[e] : 0;
  half8 qv = *(const half8*)(Qh + (size_t)src*32 + q*8);
  while(e < e1){
    int e2 = e + 8;
    int src2 = (e2 < e1) ? csr_src[e2] : 0;
    half8 qv2 = *(const half8*)(Qh + (size_t)src2*32 + q*8);
    float v[8];
    #pragma unroll
    for(int k=0;k<8;k++) v[k] = p8[k] + (float)qv[k];
    float ps = ((v[0]+v[1])+(v[2]+v[3])) + ((v[4]+v[5])+(v[6]+v[7]));
    ps += __shfl_xor(ps,1); ps += __shfl_xor(ps,2);
    float mean = ps * 0.03125f;
    float vs = 0.f;
    #pragma unroll
    for(int k=0;k<8;k++){ float dd = v[k]-mean; vs += dd*dd; v[k]=dd; }
    vs += __shfl_xor(vs,1); vs += __shfl_xor(vs,2);
    float rstd = rsqrtf(vs*0.03125f + LN_EPS);
    #pragma unroll
    for(int k=0;k<8;k++) agg8[k] += gelu_f(v[k]*rstd*mgq[k] + mbq[k]);
    qv = qv2; e = e2;
  }
  #pragma unroll
  for(int k=0;k<8;k++) agg8[k] += __shfl_xor(agg8[k], 4);
  #pragma unroll
  for(int k=0;k<8;k++) agg8[k] += __shfl_xor(agg8[k], 8);
  #pragma unroll
  for(int k=0;k<8;k++) agg8[k] += __shfl_xor(agg8[k], 16);
  if(slot==0) st8(aggO + (size_t)n*32 + q*8, agg8);
}

// -------- update MLP + next-layer PQR, 4 lanes/node --------
__global__ __launch_bounds__(256) void upd_pqr_kernel(
    const float* __restrict__ aggI, const float* __restrict__ Rio,
    const float* __restrict__ Ub,
    const float* __restrict__ ug, const float* __restrict__ ub,
    const float* __restrict__ Wm2, const float* __restrict__ bm2,
    const float* __restrict__ Wu2, const float* __restrict__ bu2,
    float* __restrict__ h,
    float* __restrict__ P, _Float16* __restrict__ Qh, float* __restrict__ Rout)
{
  int t = blockIdx.x*256 + threadIdx.x;
  int n = t >> 2, q = t & 3;
  if(n >= NN) return;
  int base = threadIdx.x & 60;
  float aggq[8], uq[8];
  ld8(aggI + (size_t)n*32 + q*8, aggq);
  ld8(Rio  + (size_t)n*32 + q*8, uq);
  #pragma unroll
  for(int m=0;m<4;m++){
    #pragma unroll
    for(int kk=0;kk<8;kk++){
      float a = __shfl(aggq[kk], base|m);
      float w[8]; ld8(Ub + (m*8+kk)*32 + q*8, w);
      #pragma unroll
      for(int j=0;j<8;j++) uq[j] += a * w[j];
    }
  }
  float sm = ((uq[0]+uq[1])+(uq[2]+uq[3])) + ((uq[4]+uq[5])+(uq[6]+uq[7]));
  sm += __shfl_xor(sm,1); sm += __shfl_xor(sm,2);
  float mean = sm * 0.03125f;
  float vs = 0.f;
  #pragma unroll
  for(int j=0;j<8;j++){ float d = uq[j]-mean; vs += d*d; uq[j]=d; }
  vs += __shfl_xor(vs,1); vs += __shfl_xor(vs,2);
  float rstd = rsqrtf(vs*0.03125f + LN_EPS);
  float ugq[8], ubq[8], hq[8];
  ld8(ug+q*8, ugq); ld8(ub+q*8, ubq);
  ld8(h + (size_t)n*32 + q*8, hq);
  #pragma unroll
  for(int j=0;j<8;j++) hq[j] += gelu_f(uq[j]*rstd*ugq[j] + ubq[j]);
  st8(h + (size_t)n*32 + q*8, hq);
  // next-layer PQR
  float apv[8], aqv[8], arv[8];
  ld8(bm2+q*8, apv); ld8(bu2+q*8, arv);
  #pragma unroll
  for(int j=0;j<8;j++) aqv[j]=0.f;
  #pragma unroll
  for(int m=0;m<4;m++){
    #pragma unroll
    for(int kk=0;kk<8;kk++){
      float hk = __shfl(hq[kk], base|m);
      int k = m*8+kk;
      float wm[8],wq[8],wu[8];
      ld8(Wm2 + k*32      + q*8, wm);
      ld8(Wm2 + (32+k)*32 + q*8, wq);
      ld8(Wu2 + k*32      + q*8, wu);
      #pragma unroll
      for(int j=0;j<8;j++){ apv[j]+=hk*wm[j]; aqv[j]+=hk*wq[j]; arv[j]+=hk*wu[j]; }
    }
  }
  st8(P    + (size_t)n*32 + q*8, apv);
  st8(Rout + (size_t)n*32 + q*8, arv);
  half8 qo;
  #pragma unroll
  for(int k=0;k<8;k++) qo[k] = (_Float16)aqv[k];
  *(half8*)(Qh + (size_t)n*32 + q*8) = qo;
}

// -------- last update + final node matmul, 4 lanes/node, split-half fp16 y --------
__global__ __launch_bounds__(256) void upd_fin_kernel(
    const float* __restrict__ aggI, const float* __restrict__ Rio,
    const float* __restrict__ Ub,
    const float* __restrict__ ug, const float* __restrict__ ub,
    const float* __restrict__ h, const float* __restrict__ pre,
    const float* __restrict__ fW1, const float* __restrict__ fbng,
    _Float16* __restrict__ y1, _Float16* __restrict__ y2)
{
  int t = blockIdx.x*256 + threadIdx.x;
  int n = t >> 2, q = t & 3;
  if(n >= NN) return;
  int base = threadIdx.x & 60;
  const float rs = rsqrtf(1.0f + LN_EPS);
  float aggq[8], uq[8];
  ld8(aggI + (size_t)n*32 + q*8, aggq);
  ld8(Rio  + (size_t)n*32 + q*8, uq);
  #pragma unroll
  for(int m=0;m<4;m++){
    #pragma unroll
    for(int kk=0;kk<8;kk++){
      float a = __shfl(aggq[kk], base|m);
      float w[8]; ld8(Ub + (m*8+kk)*32 + q*8, w);
      #pragma unroll
      for(int j=0;j<8;j++) uq[j] += a * w[j];
    }
  }
  float sm = ((uq[0]+uq[1])+(uq[2]+uq[3])) + ((uq[4]+uq[5])+(uq[6]+uq[7]));
  sm += __shfl_xor(sm,1); sm += __shfl_xor(sm,2);
  float mean = sm * 0.03125f;
  float vs = 0.f;
  #pragma unroll
  for(int j=0;j<8;j++){ float d = uq[j]-mean; vs += d*d; uq[j]=d; }
  vs += __shfl_xor(vs,1); vs += __shfl_xor(vs,2);
  float rstd = rsqrtf(vs*0.03125f + LN_EPS);
  float ugq[8], ubq[8], hq[8], pq[8];
  ld8(ug+q*8, ugq); ld8(ub+q*8, ubq);
  ld8(h   + (size_t)n*32 + q*8, hq);
  ld8(pre + (size_t)n*32 + q*8, pq);
  #pragma unroll
  for(int j=0;j<8;j++) hq[j] += gelu_f(uq[j]*rstd*ugq[j] + ubq[j]) + pq[j];
  float acc[16];
  #pragma unroll
  for(int j=0;j<16;j++) acc[j]=0.f;
  #pragma unroll
  for(int m=0;m<4;m++){
    #pragma unroll
    for(int kk=0;kk<8;kk++){
      float hk = __shfl(hq[kk], base|m);
      float w[16]; ld16(fW1 + (m*8+kk)*64 + q*16, w);
      #pragma unroll
      for(int j=0;j<16;j++) acc[j] += hk * w[j];
    }
  }
  float fg[16]; ld16(fbng + q*16, fg);
  half8 o0, o1;
  #pragma unroll
  for(int k=0;k<8;k++){
    o0[k] = (_Float16)(acc[k]   * (fg[k]*rs));
    o1[k] = (_Float16)(acc[8+k] * (fg[8+k]*rs));
  }
  _Float16* dst = (q<2) ? (y1 + (size_t)n*32 + q*16) : (y2 + (size_t)n*32 + (q-2)*16);
  ((half8*)dst)[0] = o0; ((half8*)dst)[1] = o1;
}

// ---------------- final per-edge: 4 lanes per edge, 2 edges/group, feature-split ----------------
__global__ __launch_bounds__(256) void finalA_kernel(
    const _Float16* __restrict__ y, const int* __restrict__ ei,
    const float* __restrict__ cvec, const float* __restrict__ W2,
    const float* __restrict__ b2, float* __restrict__ out)
{
  int t = blockIdx.x*256 + threadIdx.x;   // grid = NE*2 exactly
  int g = t >> 2, q = t & 3;
  int eA = g, eB = g + NE/2;
  int sA = __builtin_nontemporal_load(ei + eA);
  int dA = __builtin_nontemporal_load(ei + NE + eA);
  int sB = __builtin_nontemporal_load(ei + eB);
  int dB = __builtin_nontemporal_load(ei + NE + eB);
  half8 aA = *(const half8*)(y + (size_t)dA*32 + q*8);
  half8 cA = *(const half8*)(y + (size_t)sA*32 + q*8);
  half8 aB = *(const half8*)(y + (size_t)dB*32 + q*8);
  half8 cB = *(const half8*)(y + (size_t)sB*32 + q*8);
  float cq[8]; ld8(cvec + q*8, cq);
  float w[24]; ld8(W2+q*24, w); ld8(W2+q*24+8, w+8); ld8(W2+q*24+16, w+16);
  float oA0=0.f,oA1=0.f,oA2=0.f, oB0=0.f,oB1=0.f,oB2=0.f;
  #pragma unroll
  for(int k=0;k<8;k++){
    float tA = gelu_f(((float)aA[k]-(float)cA[k]) + cq[k]);
    float tB = gelu_f(((float)aB[k]-(float)cB[k]) + cq[k]);
    oA0 += tA*w[3*k]; oA1 += tA*w[3*k+1]; oA2 += tA*w[3*k+2];
    oB0 += tB*w[3*k]; oB1 += tB*w[3*k+1]; oB2 += tB*w[3*k+2];
  }
  oA0 += __shfl_xor(oA0,1); oA0 += __shfl_xor(oA0,2);
  oA1 += __shfl_xor(oA1,1); oA1 += __shfl_xor(oA1,2);
  oA2 += __shfl_xor(oA2,1); oA2 += __shfl_xor(oA2,2);
  oB0 += __shfl_xor(oB0,1); oB0 += __shfl_xor(oB0,2);
  oB1 += __shfl_xor(oB1,1); oB1 += __shfl_xor(oB1,2);
  oB2 += __shfl_xor(oB2,1); oB2 += __shfl_xor(oB2,2);
  float ovA = (q==0) ? oA0 + b2[0] : (q==1) ? oA1 + b2[1] : oA2 + b2[2];
  float ovB = (q==0) ? oB0 + b2[0] : (q==1) ? oB1 + b2[1] : oB2 + b2[2];
  if(q < 3){
    __builtin_nontemporal_store(ovA, out + (size_t)eA*3 + q);
    __builtin_nontemporal_store(ovB, out + (size_t)eB*3 + q);
  }
}

__global__ __launch_bounds__(256) void finalB_kernel(
    const _Float16* __restrict__ y, const int* __restrict__ ei,
    const float* __restrict__ cvec, const float* __restrict__ W2,
    float* __restrict__ out)
{
  int t = blockIdx.x*256 + threadIdx.x;
  int g = t >> 2, q = t & 3;
  int eA = g, eB = g + NE/2;
  float pA = 0.f, pB = 0.f;
  if(q < 3){
    pA = __builtin_nontemporal_load(out + (size_t)eA*3 + q);
    pB = __builtin_nontemporal_load(out + (size_t)eB*3 + q);
  }
  int sA = __builtin_nontemporal_load(ei + eA);
  int dA = __builtin_nontemporal_load(ei + NE + eA);
  int sB = __builtin_nontemporal_load(ei + eB);
  int dB = __builtin_nontemporal_load(ei + NE + eB);
  half8 aA = *(const half8*)(y + (size_t)dA*32 + q*8);
  half8 cA = *(const half8*)(y + (size_t)sA*32 + q*8);
  half8 aB = *(const half8*)(y + (size_t)dB*32 + q*8);
  half8 cB = *(const half8*)(y + (size_t)sB*32 + q*8);
  float cq[8]; ld8(cvec + q*8, cq);
  float w[24]; ld8(W2+q*24, w); ld8(W2+q*24+8, w+8); ld8(W2+q*24+16, w+16);
  float oA0=0.f,oA1=0.f,oA2=0.f, oB0=0.f,oB1=0.f,oB2=0.f;
  #pragma unroll
  for(int k=0;k<8;k++){
    float tA = gelu_f(((float)aA[k]-(float)cA[k]) + cq[k]);
    float tB = gelu_f(((float)aB[k]-(float)cB[k]) + cq[k]);
    oA0 += tA*w[3*k]; oA1 += tA*w[3*k+1]; oA2 += tA*w[3*k+2];
    oB0 += tB*w[3*k]; oB1 += tB*w[3*k+1]; oB2 += tB*w[3*k+2];
  }
  oA0 += __shfl_xor(oA0,1); oA0 += __shfl_xor(oA0,2);
  oA1 += __shfl_xor(oA1,1); oA1 += __shfl_xor(oA1,2);
  oA2 += __shfl_xor(oA2,1); oA2 += __shfl_xor(oA2,2);
  oB0 += __shfl_xor(oB0,1); oB0 += __shfl_xor(oB0,2);
  oB1 += __shfl_xor(oB1,1); oB1 += __shfl_xor(oB1,2);
  oB2 += __shfl_xor(oB2,1); oB2 += __shfl_xor(oB2,2);
  float ovA = pA + ((q==0) ? oA0 : (q==1) ? oA1 : oA2);
  float ovB = pB + ((q==0) ? oB0 : (q==1) ? oB1 : oB2);
  if(q < 3){
    __builtin_nontemporal_store(ovA, out + (size_t)eA*3 + q);
    __builtin_nontemporal_store(ovB, out + (size_t)eB*3 + q);
  }
}

extern "C" void kernel_launch(void* const* d_in, const int* in_sizes, int n_in,
                              void* d_out, int out_size, void* d_ws, size_t ws_size,
                              hipStream_t stream)
{
  (void)in_sizes; (void)n_in; (void)out_size; (void)ws_size;
  const float* x     = (const float*)d_in[0];
  const int*   ei    = (const int*)d_in[1];
  const float* eW1   = (const float*)d_in[2];
  const float* eb1   = (const float*)d_in[3];
  const float* ebn1g = (const float*)d_in[4];
  const float* ebn1b = (const float*)d_in[5];
  const float* eW2   = (const float*)d_in[6];
  const float* eb2   = (const float*)d_in[7];
  const float* ebn2g = (const float*)d_in[8];
  const float* ebn2b = (const float*)d_in[9];
  const float* msgW  = (const float*)d_in[10];
  const float* msgb  = (const float*)d_in[11];
  const float* msglng= (const float*)d_in[12];
  const float* msglnb= (const float*)d_in[13];
  const float* updW  = (const float*)d_in[14];
  const float* updb  = (const float*)d_in[15];
  const float* updlng= (const float*)d_in[16];
  const float* updlnb= (const float*)d_in[17];
  const float* fW1   = (const float*)d_in[18];
  const float* fb1   = (const float*)d_in[19];
  const float* fbng  = (const float*)d_in[20];
  const float* fbnb  = (const float*)d_in[21];
  const float* fW2   = (const float*)d_in[22];
  const float* fb2   = (const float*)d_in[23];
  float* out = (float*)d_out;

  // workspace: h, pre, P, R, agg (NN*32 f32 each), Qh (NN*16 f32), cvec, ints
  float* f   = (float*)d_ws;
  float* h   = f;
  float* pre = f + 1*(size_t)NN*32;
  float* P   = f + 2*(size_t)NN*32;
  float* R   = f + 3*(size_t)NN*32;
  float* agg = f + 4*(size_t)NN*32;
  _Float16* Qh = (_Float16*)(f + 5*(size_t)NN*32);   // NN*32 halves
  _Float16* y1 = (_Float16*)P;                        // NN*32 halves (P dead after msg2)
  _Float16* y2 = y1 + (size_t)NN*32;                  // NN*32 halves (still within P)
  float* cvec  = f + 5*(size_t)NN*32 + (size_t)NN*16; // 64 floats
  int* ip      = (int*)(cvec + 64);
  int* cnt16   = ip;                  // 16*NN (becomes offs16 after reduce16)
  int* deg     = ip + 16*NN;          // NN
  int* row_ptr = ip + 17*NN;          // NN+4
  int* csr     = ip + 18*NN + 4;      // NE
  int* rank    = (int*)agg;           // NE ints, aliases agg (free until msg layer 0)

  hipMemsetAsync(cnt16, 0, (size_t)16*NN*sizeof(int), stream);
  hist_kernel<<<391, 256, 0, stream>>>(ei, cnt16, rank);
  reduce16_kernel<<<(NN/4+255)/256, 256, 0, stream>>>(cnt16, deg);
  scan_kernel<<<1, 1024, 0, stream>>>(deg, row_ptr);
  fill_embed_kernel<<<EMB_B + FILL_B, 256, 0, stream>>>(ei, row_ptr, rank, cnt16, csr,
      x, eW1, eb1, ebn1g, ebn1b,
      eW2, eb2, ebn2g, ebn2b,
      msgW, msgb, updW, updb,
      fb1, fbng, fbnb,
      h, pre, P, Qh, R, cvec);

  for(int l=0; l<3; l++){
    msg_kernel<<<(NN*32)/256, 256, 0, stream>>>(P, Qh, row_ptr, csr,
        msglng + l*32, msglnb + l*32, agg);
    if(l < 2){
      upd_pqr_kernel<<<EMB_B, 256, 0, stream>>>(agg, R,
          updW + l*2048 + 1024, updlng + l*32, updlnb + l*32,
          msgW + (l+1)*2048, msgb + (l+1)*32,
          updW + (l+1)*2048, updb + (l+1)*32,
          h, P, Qh, R);
    } else {
      upd_fin_kernel<<<EMB_B, 256, 0, stream>>>(agg, R,
          updW + l*2048 + 1024, updlng + l*32, updlnb + l*32,
          h, pre, fW1, fbng, y1, y2);
    }
  }

  finalA_kernel<<<(NE*2)/256, 256, 0, stream>>>(y1, ei, cvec,      fW2,      fb2, out);
  finalB_kernel<<<(NE*2)/256, 256, 0, stream>>>(y2, ei, cvec + 32, fW2 + 96, out);
}